// Round 8
// baseline (669.011 us; speedup 1.0000x reference)
//
#include <hip/hip_runtime.h>
#include <math.h>

#define CC 256
#define NSP 4096
#define L2E 1.44269504088896340736f
#define SH2 (48.0f * L2E)

typedef float f32x4  __attribute__((ext_vector_type(4)));
typedef float f32x16 __attribute__((ext_vector_type(16)));
typedef _Float16 half8 __attribute__((ext_vector_type(8)));
typedef short short8 __attribute__((ext_vector_type(8)));
typedef unsigned short u16;
typedef unsigned int   u32;

__device__ __forceinline__ u16 bf16rne(float x) {
    unsigned u = __float_as_uint(x);
    u += 0x7FFFu + ((u >> 16) & 1u);
    return (u16)(u >> 16);
}
__device__ __forceinline__ half8 ld_frag(const u16* p) {
    int4 v = *(const int4*)p;
    return __builtin_bit_cast(half8, v);
}
__device__ __forceinline__ short8 ld_bfrag(const u16* p) {
    int4 v = *(const int4*)p;
    return __builtin_bit_cast(short8, v);
}
__device__ __forceinline__ u32 pkrtz(float a, float b) {
    return __builtin_bit_cast(u32, __builtin_amdgcn_cvt_pkrtz(a, b));
}
__device__ __forceinline__ u16 f16b(float x) {
    _Float16 h = (_Float16)x;
    return __builtin_bit_cast(u16, h);
}
__device__ __forceinline__ float f16f(u16 v) {
    return (float)__builtin_bit_cast(_Float16, v);
}

// ---------------------------------------------------------------------------
// wpack: W (256x256 f32) -> bf16 hi/lo, natural row-major [o][c].
// grid (64, 4 slots = W1,W2,W3,W4), 256 thr, 4 elem/thr.
// ---------------------------------------------------------------------------
__global__ __launch_bounds__(256) void wpack(
    const float* __restrict__ W1, const float* __restrict__ W2,
    const float* __restrict__ W3, const float* __restrict__ W4,
    u16* __restrict__ Whi, u16* __restrict__ Wlo)
{
    const int slot = blockIdx.y;
    const float* W = slot == 0 ? W1 : slot == 1 ? W2 : slot == 2 ? W3 : W4;
    const int i = (blockIdx.x * 256 + threadIdx.x) * 4;
    const f32x4 v = *(const f32x4*)(W + i);
    ushort4 h4, l4;
    h4.x = bf16rne(v.x); l4.x = bf16rne(v.x - __uint_as_float((u32)h4.x << 16));
    h4.y = bf16rne(v.y); l4.y = bf16rne(v.y - __uint_as_float((u32)h4.y << 16));
    h4.z = bf16rne(v.z); l4.z = bf16rne(v.z - __uint_as_float((u32)h4.z << 16));
    h4.w = bf16rne(v.w); l4.w = bf16rne(v.w - __uint_as_float((u32)h4.w << 16));
    *(ushort4*)(Whi + slot * 65536 + i) = h4;
    *(ushort4*)(Wlo + slot * 65536 + i) = l4;
}

// ---------------------------------------------------------------------------
// conv_qkv: unified K/Q/V projection MFMA GEMM (bf16 hi/lo, 3 products).
// Block 256 thr / 4 waves; tile = 256 o x 32 s; X staged once in LDS [s][c]
// bf16 hi/lo XOR-swizzled (32 KB). A-frags (W rows) from packed global (L2).
// Epilogues write flash3's verified packed layouts directly:
//   proj 0: K f16 hi/lo * L2E (chunk ui);  proj 1: Q f16 (chunk ui);
//   proj 2: V f16 TRANSPOSED frag-major (direct scatter; vpack deleted).
// grid: (128 s-tiles, 3 proj, 2 b) = 768 blocks = 3 waves/SIMD.
// ---------------------------------------------------------------------------
__global__ __launch_bounds__(256) void conv_qkv(
    const float* __restrict__ in1, const float* __restrict__ in2,
    const u16* __restrict__ Wpk_hi, const u16* __restrict__ Wpk_lo,
    const float* __restrict__ b1, const float* __restrict__ b2,
    const float* __restrict__ b3,
    u16* __restrict__ Khi, u16* __restrict__ Klo,
    u16* __restrict__ Qpk, u16* __restrict__ Vpk)
{
    __shared__ __align__(16) u16 Xhi[32 * 256];   // 16 KB, swizzled [s][c]
    __shared__ __align__(16) u16 Xlo[32 * 256];   // 16 KB

    const int tid = threadIdx.x;
    const int w = tid >> 6, l = tid & 63;
    const int h = l >> 5, ln = l & 31;
    const int st = blockIdx.x;           // 0..127
    const int proj = blockIdx.y;         // 0 K, 1 Q, 2 V
    const int b = blockIdx.z;
    const int s0 = st * 32;

    const float* x = (proj == 2) ? in2 : in1;
    const u16* Wh = Wpk_hi + proj * 65536;
    const u16* Wl = Wpk_lo + proj * 65536;
    const float* bias = proj == 0 ? b1 : proj == 1 ? b2 : b3;

    // ---- stage X tile: wave w covers c = w*64..w*64+63; lane: s = s0+ln ----
#pragma unroll
    for (int i = 0; i < 4; ++i) {
        const int c0 = w * 64 + (h * 4 + i) * 8;
        float xv[8];
#pragma unroll
        for (int cc = 0; cc < 8; ++cc)
            xv[cc] = x[((size_t)b * CC + c0 + cc) * NSP + s0 + ln];
        u32 hw[4], lw[4];
#pragma unroll
        for (int p2 = 0; p2 < 4; ++p2) {
            const u16 h0 = bf16rne(xv[2 * p2]);
            const u16 h1 = bf16rne(xv[2 * p2 + 1]);
            const u16 l0 = bf16rne(xv[2 * p2]     - __uint_as_float((u32)h0 << 16));
            const u16 l1 = bf16rne(xv[2 * p2 + 1] - __uint_as_float((u32)h1 << 16));
            hw[p2] = (u32)h0 | ((u32)h1 << 16);
            lw[p2] = (u32)l0 | ((u32)l1 << 16);
        }
        const int off = ((ln * 256 + c0) * 2) ^ ((ln & 7) << 4);
        *(uint4*)((char*)Xhi + off) = make_uint4(hw[0], hw[1], hw[2], hw[3]);
        *(uint4*)((char*)Xlo + off) = make_uint4(lw[0], lw[1], lw[2], lw[3]);
    }
    __syncthreads();

    f32x16 acc[2];
#pragma unroll
    for (int ti = 0; ti < 2; ++ti)
#pragma unroll
        for (int i = 0; i < 16; ++i) acc[ti][i] = 0.f;

#pragma unroll 2
    for (int kk = 0; kk < 16; ++kk) {
        const int kc = kk * 16 + h * 8;
        short8 ah[2], al[2];
#pragma unroll
        for (int ti = 0; ti < 2; ++ti) {
            const size_t wrow = (size_t)(w * 64 + ti * 32 + ln) * 256 + kc;
            ah[ti] = ld_bfrag(Wh + wrow);
            al[ti] = ld_bfrag(Wl + wrow);
        }
        const int off = ((ln * 256 + kc) * 2) ^ ((ln & 7) << 4);
        const short8 bh_ = *(const short8*)((const char*)Xhi + off);
        const short8 bl_ = *(const short8*)((const char*)Xlo + off);
#pragma unroll
        for (int ti = 0; ti < 2; ++ti) {
            acc[ti] = __builtin_amdgcn_mfma_f32_32x32x16_bf16(ah[ti], bh_, acc[ti], 0, 0, 0);
            acc[ti] = __builtin_amdgcn_mfma_f32_32x32x16_bf16(ah[ti], bl_, acc[ti], 0, 0, 0);
            acc[ti] = __builtin_amdgcn_mfma_f32_32x32x16_bf16(al[ti], bh_, acc[ti], 0, 0, 0);
        }
    }

    // ---- epilogue: D[row = o (reg pattern), col = s = s0+ln] ----
    const int sg = s0 + ln;
#pragma unroll
    for (int ti = 0; ti < 2; ++ti)
#pragma unroll
        for (int reg = 0; reg < 16; ++reg) {
            const int o = w * 64 + ti * 32 + (reg & 3) + 8 * (reg >> 2) + 4 * h;
            const size_t SLB = (size_t)((b * 4 + (o >> 6)) * 64 + (o & 63)) * 4096;
            const float av0 = acc[ti][reg] + bias[o];
            if (proj == 2) {
                // V frag-major: ui = ((s>>9)*64 + (s&63))*8 + ((s>>6)&7)
                const size_t ui = SLB + (size_t)((sg >> 9) * 64 + (sg & 63)) * 8 + ((sg >> 6) & 7);
                Vpk[ui] = f16b(av0);
            } else {
                const float av = (proj == 0) ? av0 * L2E : av0;
                const _Float16 hf = (_Float16)av;
                const size_t ui = SLB + (size_t)(((sg >> 3) & 7) * 64 + (sg >> 6)) * 8 + (sg & 7);
                if (proj == 0) {
                    Khi[ui] = __builtin_bit_cast(u16, hf);
                    Klo[ui] = f16b(av - (float)hf);
                } else {
                    Qpk[ui] = __builtin_bit_cast(u16, hf);
                }
            }
        }
}

// ---------------------------------------------------------------------------
// flash3: no LDS, no barriers. S^T = Q*K^T (32x32x16 f16, K hi/lo in regs,
// C-init = -48*log2e), P = exp2(S'), in-register P->A-frag via cvt_pkrtz +
// shfl_xor(32) + half-select, O += P*V.  Opart stored f16.
// grid 1024 (= 4 blocks/CU = 4 waves/SIMD): bh = id&7 (XCD-pinned),
// qq = (id>>3)&7 (tq eighth), tb = id>>6.
// ---------------------------------------------------------------------------
__global__ __launch_bounds__(256, 4) void flash3(
    const u16* __restrict__ Khi, const u16* __restrict__ Klo,
    const u16* __restrict__ Qpk, const u16* __restrict__ Vpk,
    u16* __restrict__ Oparth, float* __restrict__ zpart)
{
    const int tid = threadIdx.x;
    const int w = tid >> 6, l = tid & 63;
    const int h = l >> 5, ln = l & 31;
    const int id = blockIdx.x;
    const int bh = id & 7, qq = (id >> 3) & 7, tb = id >> 6;
    const int b = bh >> 2, hd = bh & 3;
    const int t = tb * 4 + w;

    const u16* Kh = Khi + (size_t)(bh * 64 + t) * 4096;
    const u16* Kl = Klo + (size_t)(bh * 64 + t) * 4096;

    half8 kf_h[2][4], kf_l[2][4];
#pragma unroll
    for (int rt = 0; rt < 2; ++rt)
#pragma unroll
        for (int ks = 0; ks < 4; ++ks) {
            const int cix = ((ks * 2 + h) * 64 + rt * 32 + ln) * 8;
            kf_h[rt][ks] = ld_frag(Kh + cix);
            kf_l[rt][ks] = ld_frag(Kl + cix);
        }

    f32x16 oacc[2][2];
#pragma unroll
    for (int rt = 0; rt < 2; ++rt)
#pragma unroll
        for (int ft = 0; ft < 2; ++ft)
#pragma unroll
            for (int i = 0; i < 16; ++i) oacc[rt][ft][i] = 0.f;
    float zacc[2] = {0.f, 0.f};

    for (int it = 0; it < 8; ++it) {
        const int tq = qq * 8 + it;
        const u16* Qt = Qpk + (size_t)(bh * 64 + tq) * 4096;
        const u16* Vt = Vpk + (size_t)(bh * 64 + tq) * 4096;
#pragma unroll
        for (int jt = 0; jt < 2; ++jt) {
            half8 qf[4];
#pragma unroll
            for (int ks = 0; ks < 4; ++ks)
                qf[ks] = ld_frag(Qt + ((ks * 2 + h) * 64 + jt * 32 + ln) * 8);

            f32x16 sa[2];
#pragma unroll
            for (int rt = 0; rt < 2; ++rt)
#pragma unroll
                for (int i = 0; i < 16; ++i) sa[rt][i] = -SH2;
#pragma unroll
            for (int ks = 0; ks < 4; ++ks) {
                sa[0] = __builtin_amdgcn_mfma_f32_32x32x16_f16(qf[ks], kf_h[0][ks], sa[0], 0, 0, 0);
                sa[1] = __builtin_amdgcn_mfma_f32_32x32x16_f16(qf[ks], kf_h[1][ks], sa[1], 0, 0, 0);
                sa[0] = __builtin_amdgcn_mfma_f32_32x32x16_f16(qf[ks], kf_l[0][ks], sa[0], 0, 0, 0);
                sa[1] = __builtin_amdgcn_mfma_f32_32x32x16_f16(qf[ks], kf_l[1][ks], sa[1], 0, 0, 0);
            }

            half8 vf[2][2];
#pragma unroll
            for (int js = 0; js < 2; ++js)
#pragma unroll
                for (int ft = 0; ft < 2; ++ft)
                    vf[js][ft] = ld_frag(Vt + (((jt * 2 + js) * 2 + h) * 64 + ft * 32 + ln) * 8);

#pragma unroll
            for (int rt = 0; rt < 2; ++rt) {
                float p[16]; float zs = 0.f;
#pragma unroll
                for (int i = 0; i < 16; ++i) { p[i] = exp2f(sa[rt][i]); zs += p[i]; }
                zacc[rt] += zs;
                u32 wd[8], sw[8];
#pragma unroll
                for (int i = 0; i < 8; ++i) wd[i] = pkrtz(p[2 * i], p[2 * i + 1]);
#pragma unroll
                for (int i = 0; i < 8; ++i) sw[i] = (u32)__shfl_xor((int)wd[i], 32);
                int4 c0 = make_int4((int)(h ? sw[2] : wd[0]), (int)(h ? sw[3] : wd[1]),
                                    (int)(h ? wd[2] : sw[0]), (int)(h ? wd[3] : sw[1]));
                int4 c1 = make_int4((int)(h ? sw[6] : wd[4]), (int)(h ? sw[7] : wd[5]),
                                    (int)(h ? wd[6] : sw[4]), (int)(h ? wd[7] : sw[5]));
                const half8 pf0 = __builtin_bit_cast(half8, c0);
                const half8 pf1 = __builtin_bit_cast(half8, c1);
                oacc[rt][0] = __builtin_amdgcn_mfma_f32_32x32x16_f16(pf0, vf[0][0], oacc[rt][0], 0, 0, 0);
                oacc[rt][0] = __builtin_amdgcn_mfma_f32_32x32x16_f16(pf1, vf[1][0], oacc[rt][0], 0, 0, 0);
                oacc[rt][1] = __builtin_amdgcn_mfma_f32_32x32x16_f16(pf0, vf[0][1], oacc[rt][1], 0, 0, 0);
                oacc[rt][1] = __builtin_amdgcn_mfma_f32_32x32x16_f16(pf1, vf[1][1], oacc[rt][1], 0, 0, 0);
            }
        }
    }

#pragma unroll
    for (int rt = 0; rt < 2; ++rt) {
        const float z2 = zacc[rt] + __shfl_xor(zacc[rt], 32);
        if (h == 0)
            zpart[((size_t)qq * 8 + bh) * NSP + t * 64 + rt * 32 + ln] = z2;
    }
    const size_t ob = ((size_t)(qq * 2 + b) * CC + hd * 64 + t) * NSP;
#pragma unroll
    for (int rt = 0; rt < 2; ++rt)
#pragma unroll
        for (int ft = 0; ft < 2; ++ft)
#pragma unroll
            for (int reg = 0; reg < 16; ++reg) {
                const int rin = (reg & 3) + 8 * (reg >> 2) + 4 * h;
                Oparth[ob + (size_t)(rt * 32 + rin) * 64 + ft * 32 + ln]
                    = f16b(oacc[rt][ft][reg]);
            }
}

// ---------------------------------------------------------------------------
__global__ __launch_bounds__(256) void reduce_kernel(
    const float* __restrict__ zp, float* __restrict__ coef)
{
    __shared__ float red[256];
    const int tid = threadIdx.x, bh = blockIdx.x;
    float lz = 0.f;
    for (int i = tid; i < 8 * NSP; i += 256) {
        const int qq = i >> 12, r = i & 4095;
        lz += zp[((size_t)qq * 8 + bh) * NSP + r];
    }
    red[tid] = lz; __syncthreads();
    for (int s = 128; s > 0; s >>= 1) {
        if (tid < s) red[tid] += red[tid + s];
        __syncthreads();
    }
    if (tid == 0) coef[bh] = 1.f / red[0];
}

// ---------------------------------------------------------------------------
// conv_out: out = W4 . (sum of 8 f16 partials * coef) + b4, f32, MFMA.
// Block 256 thr / 4 waves; tile = 128 o (oh half) x 32 s; grid (128,2,2)=512.
// ---------------------------------------------------------------------------
__global__ __launch_bounds__(256) void conv_out(
    const u16* __restrict__ Oparth,
    const u16* __restrict__ Wpk_hi, const u16* __restrict__ Wpk_lo,
    const float* __restrict__ b4, const float* __restrict__ coef,
    float* __restrict__ out)
{
    __shared__ __align__(16) u16 Xhi[32 * 256];   // 16 KB
    __shared__ __align__(16) u16 Xlo[32 * 256];   // 16 KB

    const int tid = threadIdx.x;
    const int w = tid >> 6, l = tid & 63;
    const int h = l >> 5, ln = l & 31;
    const int st = blockIdx.x;           // 0..127
    const int oh = blockIdx.y;           // o half
    const int b = blockIdx.z;
    const int s0 = st * 32;

    const u16* Wh = Wpk_hi + 3 * 65536;
    const u16* Wl = Wpk_lo + 3 * 65536;
    const size_t TENu = (size_t)2 * CC * NSP;

    // ---- stage: sum 8 f16 partials * coef -> bf16 hi/lo LDS ----
    const float cf = coef[b * 4 + w];
#pragma unroll
    for (int i = 0; i < 4; ++i) {
        const int c0 = w * 64 + (h * 4 + i) * 8;
        float xv[8];
#pragma unroll
        for (int cc = 0; cc < 8; ++cc) {
            const size_t base = ((size_t)b * CC + c0 + cc) * NSP + s0 + ln;
            float s = 0.f;
#pragma unroll
            for (int pp = 0; pp < 8; ++pp)
                s += f16f(Oparth[pp * TENu + base]);
            xv[cc] = s * cf;
        }
        u32 hw[4], lw[4];
#pragma unroll
        for (int p2 = 0; p2 < 4; ++p2) {
            const u16 h0 = bf16rne(xv[2 * p2]);
            const u16 h1 = bf16rne(xv[2 * p2 + 1]);
            const u16 l0 = bf16rne(xv[2 * p2]     - __uint_as_float((u32)h0 << 16));
            const u16 l1 = bf16rne(xv[2 * p2 + 1] - __uint_as_float((u32)h1 << 16));
            hw[p2] = (u32)h0 | ((u32)h1 << 16);
            lw[p2] = (u32)l0 | ((u32)l1 << 16);
        }
        const int off = ((ln * 256 + c0) * 2) ^ ((ln & 7) << 4);
        *(uint4*)((char*)Xhi + off) = make_uint4(hw[0], hw[1], hw[2], hw[3]);
        *(uint4*)((char*)Xlo + off) = make_uint4(lw[0], lw[1], lw[2], lw[3]);
    }
    __syncthreads();

    f32x16 acc;
#pragma unroll
    for (int i = 0; i < 16; ++i) acc[i] = 0.f;

#pragma unroll 2
    for (int kk = 0; kk < 16; ++kk) {
        const int kc = kk * 16 + h * 8;
        const size_t wrow = (size_t)(oh * 128 + w * 32 + ln) * 256 + kc;
        const short8 ah = ld_bfrag(Wh + wrow);
        const short8 al = ld_bfrag(Wl + wrow);
        const int off = ((ln * 256 + kc) * 2) ^ ((ln & 7) << 4);
        const short8 bh_ = *(const short8*)((const char*)Xhi + off);
        const short8 bl_ = *(const short8*)((const char*)Xlo + off);
        acc = __builtin_amdgcn_mfma_f32_32x32x16_bf16(ah, bh_, acc, 0, 0, 0);
        acc = __builtin_amdgcn_mfma_f32_32x32x16_bf16(ah, bl_, acc, 0, 0, 0);
        acc = __builtin_amdgcn_mfma_f32_32x32x16_bf16(al, bh_, acc, 0, 0, 0);
    }

    const int sg = s0 + ln;
#pragma unroll
    for (int reg = 0; reg < 16; ++reg) {
        const int o = oh * 128 + w * 32 + (reg & 3) + 8 * (reg >> 2) + 4 * h;
        out[((size_t)b * CC + o) * NSP + sg] = acc[reg] + b4[o];
    }
}

// ---------------------------------------------------------------------------
extern "C" void kernel_launch(void* const* d_in, const int* in_sizes, int n_in,
                              void* d_out, int out_size, void* d_ws, size_t ws_size,
                              hipStream_t stream)
{
    (void)in_sizes; (void)n_in; (void)out_size; (void)ws_size;
    const float* in1 = (const float*)d_in[0];
    const float* in2 = (const float*)d_in[1];
    const float* W1 = (const float*)d_in[2]; const float* b1 = (const float*)d_in[3];
    const float* W2 = (const float*)d_in[4]; const float* b2 = (const float*)d_in[5];
    const float* W3 = (const float*)d_in[6]; const float* b3 = (const float*)d_in[7];
    const float* W4 = (const float*)d_in[8]; const float* b4 = (const float*)d_in[9];
    float* out = (float*)d_out;

    const size_t TEN = (size_t)2 * CC * NSP;          // 2,097,152 elements
    char* p = (char*)d_ws;
    u16* Khi = (u16*)p; p += TEN * 2;                 // 4 MB each
    u16* Klo = (u16*)p; p += TEN * 2;
    u16* Qpk = (u16*)p; p += TEN * 2;
    u16* Vpk = (u16*)p; p += TEN * 2;
    u16* Wph = (u16*)p; p += 4 * 65536 * 2;           // 512 KB
    u16* Wpl = (u16*)p; p += 4 * 65536 * 2;           // 512 KB
    u16* Oparth = (u16*)p; p += 8 * TEN * 2;          // 32 MB (8 f16 partials)
    float* zpart = (float*)p; p += (size_t)8 * 8 * NSP * 4;   // 1 MB
    float* coef  = (float*)p;

    wpack<<<dim3(64, 4), 256, 0, stream>>>(W1, W2, W3, W4, Wph, Wpl);
    conv_qkv<<<dim3(128, 3, 2), 256, 0, stream>>>(
        in1, in2, Wph, Wpl, b1, b2, b3, Khi, Klo, Qpk, Vpk);
    flash3<<<dim3(1024), 256, 0, stream>>>(Khi, Klo, Qpk, Vpk, Oparth, zpart);
    reduce_kernel<<<dim3(8), 256, 0, stream>>>(zpart, coef);
    conv_out<<<dim3(128, 2, 2), 256, 0, stream>>>(Oparth, Wph, Wpl, b4, coef, out);
}

// Round 9
// 171.596 us; speedup vs baseline: 3.8988x; 3.8988x over previous
//
#include <hip/hip_runtime.h>
#include <math.h>

#define CC 256
#define NSP 4096
#define L2E 1.44269504088896340736f
#define SH2 (48.0f * L2E)

typedef float f32x4  __attribute__((ext_vector_type(4)));
typedef float f32x16 __attribute__((ext_vector_type(16)));
typedef _Float16 half8 __attribute__((ext_vector_type(8)));
typedef short short8 __attribute__((ext_vector_type(8)));
typedef unsigned short u16;
typedef unsigned int   u32;

__device__ __forceinline__ u16 bf16rne(float x) {
    unsigned u = __float_as_uint(x);
    u += 0x7FFFu + ((u >> 16) & 1u);
    return (u16)(u >> 16);
}
__device__ __forceinline__ half8 ld_frag(const u16* p) {
    int4 v = *(const int4*)p;
    return __builtin_bit_cast(half8, v);
}
__device__ __forceinline__ short8 ld_bfrag(const u16* p) {
    int4 v = *(const int4*)p;
    return __builtin_bit_cast(short8, v);
}
__device__ __forceinline__ u32 pkrtz(float a, float b) {
    return __builtin_bit_cast(u32, __builtin_amdgcn_cvt_pkrtz(a, b));
}
__device__ __forceinline__ u16 f16b(float x) {
    _Float16 h = (_Float16)x;
    return __builtin_bit_cast(u16, h);
}
__device__ __forceinline__ float f16f(u16 v) {
    return (float)__builtin_bit_cast(_Float16, v);
}

// ---------------------------------------------------------------------------
// wpack: W (256x256 f32) -> bf16 hi/lo, natural row-major [o][c].
// grid (64, 4 slots = W1,W2,W3,W4), 256 thr, 4 elem/thr.
// ---------------------------------------------------------------------------
__global__ __launch_bounds__(256) void wpack(
    const float* __restrict__ W1, const float* __restrict__ W2,
    const float* __restrict__ W3, const float* __restrict__ W4,
    u16* __restrict__ Whi, u16* __restrict__ Wlo)
{
    const int slot = blockIdx.y;
    const float* W = slot == 0 ? W1 : slot == 1 ? W2 : slot == 2 ? W3 : W4;
    const int i = (blockIdx.x * 256 + threadIdx.x) * 4;
    const f32x4 v = *(const f32x4*)(W + i);
    ushort4 h4, l4;
    h4.x = bf16rne(v.x); l4.x = bf16rne(v.x - __uint_as_float((u32)h4.x << 16));
    h4.y = bf16rne(v.y); l4.y = bf16rne(v.y - __uint_as_float((u32)h4.y << 16));
    h4.z = bf16rne(v.z); l4.z = bf16rne(v.z - __uint_as_float((u32)h4.z << 16));
    h4.w = bf16rne(v.w); l4.w = bf16rne(v.w - __uint_as_float((u32)h4.w << 16));
    *(ushort4*)(Whi + slot * 65536 + i) = h4;
    *(ushort4*)(Wlo + slot * 65536 + i) = l4;
}

// ---------------------------------------------------------------------------
// conv_qkv: unified K/Q/V projection MFMA GEMM (bf16 hi/lo, 3 products).
// Block 256 thr / 4 waves; tile = 256 o x 32 s; X staged once in LDS [s][c]
// bf16 hi/lo XOR-swizzled (32 KB). A-frags (W rows) from packed global (L2).
// Epilogues write flash3's verified packed layouts directly.
// grid: (128 s-tiles, 3 proj, 2 b) = 768 blocks = 3 waves/SIMD.
// ---------------------------------------------------------------------------
__global__ __launch_bounds__(256) void conv_qkv(
    const float* __restrict__ in1, const float* __restrict__ in2,
    const u16* __restrict__ Wpk_hi, const u16* __restrict__ Wpk_lo,
    const float* __restrict__ b1, const float* __restrict__ b2,
    const float* __restrict__ b3,
    u16* __restrict__ Khi, u16* __restrict__ Klo,
    u16* __restrict__ Qpk, u16* __restrict__ Vpk)
{
    __shared__ __align__(16) u16 Xhi[32 * 256];   // 16 KB, swizzled [s][c]
    __shared__ __align__(16) u16 Xlo[32 * 256];   // 16 KB

    const int tid = threadIdx.x;
    const int w = tid >> 6, l = tid & 63;
    const int h = l >> 5, ln = l & 31;
    const int st = blockIdx.x;           // 0..127
    const int proj = blockIdx.y;         // 0 K, 1 Q, 2 V
    const int b = blockIdx.z;
    const int s0 = st * 32;

    const float* x = (proj == 2) ? in2 : in1;
    const u16* Wh = Wpk_hi + proj * 65536;
    const u16* Wl = Wpk_lo + proj * 65536;
    const float* bias = proj == 0 ? b1 : proj == 1 ? b2 : b3;

    // ---- stage X tile: wave w covers c = w*64..w*64+63; lane: s = s0+ln ----
#pragma unroll
    for (int i = 0; i < 4; ++i) {
        const int c0 = w * 64 + (h * 4 + i) * 8;
        float xv[8];
#pragma unroll
        for (int cc = 0; cc < 8; ++cc)
            xv[cc] = x[((size_t)b * CC + c0 + cc) * NSP + s0 + ln];
        u32 hw[4], lw[4];
#pragma unroll
        for (int p2 = 0; p2 < 4; ++p2) {
            const u16 h0 = bf16rne(xv[2 * p2]);
            const u16 h1 = bf16rne(xv[2 * p2 + 1]);
            const u16 l0 = bf16rne(xv[2 * p2]     - __uint_as_float((u32)h0 << 16));
            const u16 l1 = bf16rne(xv[2 * p2 + 1] - __uint_as_float((u32)h1 << 16));
            hw[p2] = (u32)h0 | ((u32)h1 << 16);
            lw[p2] = (u32)l0 | ((u32)l1 << 16);
        }
        const int off = ((ln * 256 + c0) * 2) ^ ((ln & 7) << 4);
        *(uint4*)((char*)Xhi + off) = make_uint4(hw[0], hw[1], hw[2], hw[3]);
        *(uint4*)((char*)Xlo + off) = make_uint4(lw[0], lw[1], lw[2], lw[3]);
    }
    __syncthreads();

    f32x16 acc[2];
#pragma unroll
    for (int ti = 0; ti < 2; ++ti)
#pragma unroll
        for (int i = 0; i < 16; ++i) acc[ti][i] = 0.f;

#pragma unroll 2
    for (int kk = 0; kk < 16; ++kk) {
        const int kc = kk * 16 + h * 8;
        short8 ah[2], al[2];
#pragma unroll
        for (int ti = 0; ti < 2; ++ti) {
            const size_t wrow = (size_t)(w * 64 + ti * 32 + ln) * 256 + kc;
            ah[ti] = ld_bfrag(Wh + wrow);
            al[ti] = ld_bfrag(Wl + wrow);
        }
        const int off = ((ln * 256 + kc) * 2) ^ ((ln & 7) << 4);
        const short8 bh_ = *(const short8*)((const char*)Xhi + off);
        const short8 bl_ = *(const short8*)((const char*)Xlo + off);
#pragma unroll
        for (int ti = 0; ti < 2; ++ti) {
            acc[ti] = __builtin_amdgcn_mfma_f32_32x32x16_bf16(ah[ti], bh_, acc[ti], 0, 0, 0);
            acc[ti] = __builtin_amdgcn_mfma_f32_32x32x16_bf16(ah[ti], bl_, acc[ti], 0, 0, 0);
            acc[ti] = __builtin_amdgcn_mfma_f32_32x32x16_bf16(al[ti], bh_, acc[ti], 0, 0, 0);
        }
    }

    // ---- epilogue: D[row = o (reg pattern), col = s = s0+ln] ----
    const int sg = s0 + ln;
#pragma unroll
    for (int ti = 0; ti < 2; ++ti)
#pragma unroll
        for (int reg = 0; reg < 16; ++reg) {
            const int o = w * 64 + ti * 32 + (reg & 3) + 8 * (reg >> 2) + 4 * h;
            const size_t SLB = (size_t)((b * 4 + (o >> 6)) * 64 + (o & 63)) * 4096;
            const float av0 = acc[ti][reg] + bias[o];
            if (proj == 2) {
                // V frag-major: ui = ((s>>9)*64 + (s&63))*8 + ((s>>6)&7)
                const size_t ui = SLB + (size_t)((sg >> 9) * 64 + (sg & 63)) * 8 + ((sg >> 6) & 7);
                Vpk[ui] = f16b(av0);
            } else {
                const float av = (proj == 0) ? av0 * L2E : av0;
                const _Float16 hf = (_Float16)av;
                const size_t ui = SLB + (size_t)(((sg >> 3) & 7) * 64 + (sg >> 6)) * 8 + (sg & 7);
                if (proj == 0) {
                    Khi[ui] = __builtin_bit_cast(u16, hf);
                    Klo[ui] = f16b(av - (float)hf);
                } else {
                    Qpk[ui] = __builtin_bit_cast(u16, hf);
                }
            }
        }
}

// ---------------------------------------------------------------------------
// flash3: no LDS, no barriers. S^T = Q*K^T (32x32x16 f16, K hi/lo in regs,
// C-init = -48*log2e), P = exp2(S'), in-register P->A-frag via cvt_pkrtz +
// shfl_xor(32) + half-select, O += P*V.  Opart stored f16.
// grid 1024 (4 blocks/CU): bh = id&7 (XCD-pinned), qq = (id>>3)&7, tb = id>>6.
// NOTE: launch_bounds min-waves arg MUST stay 2 — (256,4) caps VGPR at 64 and
// spills the 120-reg live state to scratch (R8: 1 GB/dispatch fetch, 6.5x).
// At the natural ~120 VGPR, 4 blocks/CU are resident anyway (120 <= 128).
// ---------------------------------------------------------------------------
__global__ __launch_bounds__(256, 2) void flash3(
    const u16* __restrict__ Khi, const u16* __restrict__ Klo,
    const u16* __restrict__ Qpk, const u16* __restrict__ Vpk,
    u16* __restrict__ Oparth, float* __restrict__ zpart)
{
    const int tid = threadIdx.x;
    const int w = tid >> 6, l = tid & 63;
    const int h = l >> 5, ln = l & 31;
    const int id = blockIdx.x;
    const int bh = id & 7, qq = (id >> 3) & 7, tb = id >> 6;
    const int b = bh >> 2, hd = bh & 3;
    const int t = tb * 4 + w;

    const u16* Kh = Khi + (size_t)(bh * 64 + t) * 4096;
    const u16* Kl = Klo + (size_t)(bh * 64 + t) * 4096;

    half8 kf_h[2][4], kf_l[2][4];
#pragma unroll
    for (int rt = 0; rt < 2; ++rt)
#pragma unroll
        for (int ks = 0; ks < 4; ++ks) {
            const int cix = ((ks * 2 + h) * 64 + rt * 32 + ln) * 8;
            kf_h[rt][ks] = ld_frag(Kh + cix);
            kf_l[rt][ks] = ld_frag(Kl + cix);
        }

    f32x16 oacc[2][2];
#pragma unroll
    for (int rt = 0; rt < 2; ++rt)
#pragma unroll
        for (int ft = 0; ft < 2; ++ft)
#pragma unroll
            for (int i = 0; i < 16; ++i) oacc[rt][ft][i] = 0.f;
    float zacc[2] = {0.f, 0.f};

    for (int it = 0; it < 8; ++it) {
        const int tq = qq * 8 + it;
        const u16* Qt = Qpk + (size_t)(bh * 64 + tq) * 4096;
        const u16* Vt = Vpk + (size_t)(bh * 64 + tq) * 4096;
#pragma unroll
        for (int jt = 0; jt < 2; ++jt) {
            half8 qf[4];
#pragma unroll
            for (int ks = 0; ks < 4; ++ks)
                qf[ks] = ld_frag(Qt + ((ks * 2 + h) * 64 + jt * 32 + ln) * 8);

            f32x16 sa[2];
#pragma unroll
            for (int rt = 0; rt < 2; ++rt)
#pragma unroll
                for (int i = 0; i < 16; ++i) sa[rt][i] = -SH2;
#pragma unroll
            for (int ks = 0; ks < 4; ++ks) {
                sa[0] = __builtin_amdgcn_mfma_f32_32x32x16_f16(qf[ks], kf_h[0][ks], sa[0], 0, 0, 0);
                sa[1] = __builtin_amdgcn_mfma_f32_32x32x16_f16(qf[ks], kf_h[1][ks], sa[1], 0, 0, 0);
                sa[0] = __builtin_amdgcn_mfma_f32_32x32x16_f16(qf[ks], kf_l[0][ks], sa[0], 0, 0, 0);
                sa[1] = __builtin_amdgcn_mfma_f32_32x32x16_f16(qf[ks], kf_l[1][ks], sa[1], 0, 0, 0);
            }

            half8 vf[2][2];
#pragma unroll
            for (int js = 0; js < 2; ++js)
#pragma unroll
                for (int ft = 0; ft < 2; ++ft)
                    vf[js][ft] = ld_frag(Vt + (((jt * 2 + js) * 2 + h) * 64 + ft * 32 + ln) * 8);

#pragma unroll
            for (int rt = 0; rt < 2; ++rt) {
                float p[16]; float zs = 0.f;
#pragma unroll
                for (int i = 0; i < 16; ++i) { p[i] = exp2f(sa[rt][i]); zs += p[i]; }
                zacc[rt] += zs;
                u32 wd[8], sw[8];
#pragma unroll
                for (int i = 0; i < 8; ++i) wd[i] = pkrtz(p[2 * i], p[2 * i + 1]);
#pragma unroll
                for (int i = 0; i < 8; ++i) sw[i] = (u32)__shfl_xor((int)wd[i], 32);
                int4 c0 = make_int4((int)(h ? sw[2] : wd[0]), (int)(h ? sw[3] : wd[1]),
                                    (int)(h ? wd[2] : sw[0]), (int)(h ? wd[3] : sw[1]));
                int4 c1 = make_int4((int)(h ? sw[6] : wd[4]), (int)(h ? sw[7] : wd[5]),
                                    (int)(h ? wd[6] : sw[4]), (int)(h ? wd[7] : sw[5]));
                const half8 pf0 = __builtin_bit_cast(half8, c0);
                const half8 pf1 = __builtin_bit_cast(half8, c1);
                oacc[rt][0] = __builtin_amdgcn_mfma_f32_32x32x16_f16(pf0, vf[0][0], oacc[rt][0], 0, 0, 0);
                oacc[rt][0] = __builtin_amdgcn_mfma_f32_32x32x16_f16(pf1, vf[1][0], oacc[rt][0], 0, 0, 0);
                oacc[rt][1] = __builtin_amdgcn_mfma_f32_32x32x16_f16(pf0, vf[0][1], oacc[rt][1], 0, 0, 0);
                oacc[rt][1] = __builtin_amdgcn_mfma_f32_32x32x16_f16(pf1, vf[1][1], oacc[rt][1], 0, 0, 0);
            }
        }
    }

#pragma unroll
    for (int rt = 0; rt < 2; ++rt) {
        const float z2 = zacc[rt] + __shfl_xor(zacc[rt], 32);
        if (h == 0)
            zpart[((size_t)qq * 8 + bh) * NSP + t * 64 + rt * 32 + ln] = z2;
    }
    const size_t ob = ((size_t)(qq * 2 + b) * CC + hd * 64 + t) * NSP;
#pragma unroll
    for (int rt = 0; rt < 2; ++rt)
#pragma unroll
        for (int ft = 0; ft < 2; ++ft)
#pragma unroll
            for (int reg = 0; reg < 16; ++reg) {
                const int rin = (reg & 3) + 8 * (reg >> 2) + 4 * h;
                Oparth[ob + (size_t)(rt * 32 + rin) * 64 + ft * 32 + ln]
                    = f16b(oacc[rt][ft][reg]);
            }
}

// ---------------------------------------------------------------------------
__global__ __launch_bounds__(256) void reduce_kernel(
    const float* __restrict__ zp, float* __restrict__ coef)
{
    __shared__ float red[256];
    const int tid = threadIdx.x, bh = blockIdx.x;
    float lz = 0.f;
    for (int i = tid; i < 8 * NSP; i += 256) {
        const int qq = i >> 12, r = i & 4095;
        lz += zp[((size_t)qq * 8 + bh) * NSP + r];
    }
    red[tid] = lz; __syncthreads();
    for (int s = 128; s > 0; s >>= 1) {
        if (tid < s) red[tid] += red[tid + s];
        __syncthreads();
    }
    if (tid == 0) coef[bh] = 1.f / red[0];
}

// ---------------------------------------------------------------------------
// conv_out: out = W4 . (sum of 8 f16 partials * coef) + b4, f32, MFMA.
// Block 256 thr / 4 waves; tile = 128 o (oh half) x 32 s; grid (128,2,2)=512.
// ---------------------------------------------------------------------------
__global__ __launch_bounds__(256) void conv_out(
    const u16* __restrict__ Oparth,
    const u16* __restrict__ Wpk_hi, const u16* __restrict__ Wpk_lo,
    const float* __restrict__ b4, const float* __restrict__ coef,
    float* __restrict__ out)
{
    __shared__ __align__(16) u16 Xhi[32 * 256];   // 16 KB
    __shared__ __align__(16) u16 Xlo[32 * 256];   // 16 KB

    const int tid = threadIdx.x;
    const int w = tid >> 6, l = tid & 63;
    const int h = l >> 5, ln = l & 31;
    const int st = blockIdx.x;           // 0..127
    const int oh = blockIdx.y;           // o half
    const int b = blockIdx.z;
    const int s0 = st * 32;

    const u16* Wh = Wpk_hi + 3 * 65536;
    const u16* Wl = Wpk_lo + 3 * 65536;
    const size_t TENu = (size_t)2 * CC * NSP;

    // ---- stage: sum 8 f16 partials * coef -> bf16 hi/lo LDS ----
    const float cf = coef[b * 4 + w];
#pragma unroll
    for (int i = 0; i < 4; ++i) {
        const int c0 = w * 64 + (h * 4 + i) * 8;
        float xv[8];
#pragma unroll
        for (int cc = 0; cc < 8; ++cc) {
            const size_t base = ((size_t)b * CC + c0 + cc) * NSP + s0 + ln;
            float s = 0.f;
#pragma unroll
            for (int pp = 0; pp < 8; ++pp)
                s += f16f(Oparth[pp * TENu + base]);
            xv[cc] = s * cf;
        }
        u32 hw[4], lw[4];
#pragma unroll
        for (int p2 = 0; p2 < 4; ++p2) {
            const u16 h0 = bf16rne(xv[2 * p2]);
            const u16 h1 = bf16rne(xv[2 * p2 + 1]);
            const u16 l0 = bf16rne(xv[2 * p2]     - __uint_as_float((u32)h0 << 16));
            const u16 l1 = bf16rne(xv[2 * p2 + 1] - __uint_as_float((u32)h1 << 16));
            hw[p2] = (u32)h0 | ((u32)h1 << 16);
            lw[p2] = (u32)l0 | ((u32)l1 << 16);
        }
        const int off = ((ln * 256 + c0) * 2) ^ ((ln & 7) << 4);
        *(uint4*)((char*)Xhi + off) = make_uint4(hw[0], hw[1], hw[2], hw[3]);
        *(uint4*)((char*)Xlo + off) = make_uint4(lw[0], lw[1], lw[2], lw[3]);
    }
    __syncthreads();

    f32x16 acc;
#pragma unroll
    for (int i = 0; i < 16; ++i) acc[i] = 0.f;

#pragma unroll 2
    for (int kk = 0; kk < 16; ++kk) {
        const int kc = kk * 16 + h * 8;
        const size_t wrow = (size_t)(oh * 128 + w * 32 + ln) * 256 + kc;
        const short8 ah = ld_bfrag(Wh + wrow);
        const short8 al = ld_bfrag(Wl + wrow);
        const int off = ((ln * 256 + kc) * 2) ^ ((ln & 7) << 4);
        const short8 bh_ = *(const short8*)((const char*)Xhi + off);
        const short8 bl_ = *(const short8*)((const char*)Xlo + off);
        acc = __builtin_amdgcn_mfma_f32_32x32x16_bf16(ah, bh_, acc, 0, 0, 0);
        acc = __builtin_amdgcn_mfma_f32_32x32x16_bf16(ah, bl_, acc, 0, 0, 0);
        acc = __builtin_amdgcn_mfma_f32_32x32x16_bf16(al, bh_, acc, 0, 0, 0);
    }

    const int sg = s0 + ln;
#pragma unroll
    for (int reg = 0; reg < 16; ++reg) {
        const int o = oh * 128 + w * 32 + (reg & 3) + 8 * (reg >> 2) + 4 * h;
        out[((size_t)b * CC + o) * NSP + sg] = acc[reg] + b4[o];
    }
}

// ---------------------------------------------------------------------------
extern "C" void kernel_launch(void* const* d_in, const int* in_sizes, int n_in,
                              void* d_out, int out_size, void* d_ws, size_t ws_size,
                              hipStream_t stream)
{
    (void)in_sizes; (void)n_in; (void)out_size; (void)ws_size;
    const float* in1 = (const float*)d_in[0];
    const float* in2 = (const float*)d_in[1];
    const float* W1 = (const float*)d_in[2]; const float* b1 = (const float*)d_in[3];
    const float* W2 = (const float*)d_in[4]; const float* b2 = (const float*)d_in[5];
    const float* W3 = (const float*)d_in[6]; const float* b3 = (const float*)d_in[7];
    const float* W4 = (const float*)d_in[8]; const float* b4 = (const float*)d_in[9];
    float* out = (float*)d_out;

    const size_t TEN = (size_t)2 * CC * NSP;          // 2,097,152 elements
    char* p = (char*)d_ws;
    u16* Khi = (u16*)p; p += TEN * 2;                 // 4 MB each
    u16* Klo = (u16*)p; p += TEN * 2;
    u16* Qpk = (u16*)p; p += TEN * 2;
    u16* Vpk = (u16*)p; p += TEN * 2;
    u16* Wph = (u16*)p; p += 4 * 65536 * 2;           // 512 KB
    u16* Wpl = (u16*)p; p += 4 * 65536 * 2;           // 512 KB
    u16* Oparth = (u16*)p; p += 8 * TEN * 2;          // 32 MB (8 f16 partials)
    float* zpart = (float*)p; p += (size_t)8 * 8 * NSP * 4;   // 1 MB
    float* coef  = (float*)p;

    wpack<<<dim3(64, 4), 256, 0, stream>>>(W1, W2, W3, W4, Wph, Wpl);
    conv_qkv<<<dim3(128, 3, 2), 256, 0, stream>>>(
        in1, in2, Wph, Wpl, b1, b2, b3, Khi, Klo, Qpk, Vpk);
    flash3<<<dim3(1024), 256, 0, stream>>>(Khi, Klo, Qpk, Vpk, Oparth, zpart);
    reduce_kernel<<<dim3(8), 256, 0, stream>>>(zpart, coef);
    conv_out<<<dim3(128, 2, 2), 256, 0, stream>>>(Oparth, Wph, Wpl, b4, coef, out);
}

// Round 10
// 155.133 us; speedup vs baseline: 4.3125x; 1.1061x over previous
//
#include <hip/hip_runtime.h>
#include <math.h>

#define CC 256
#define NSP 4096
#define L2E 1.44269504088896340736f
#define SH2 (48.0f * L2E)

typedef float f32x4  __attribute__((ext_vector_type(4)));
typedef float f32x16 __attribute__((ext_vector_type(16)));
typedef _Float16 half8 __attribute__((ext_vector_type(8)));
typedef short short8 __attribute__((ext_vector_type(8)));
typedef unsigned short u16;
typedef unsigned int   u32;

__device__ __forceinline__ u16 bf16rne(float x) {
    unsigned u = __float_as_uint(x);
    u += 0x7FFFu + ((u >> 16) & 1u);
    return (u16)(u >> 16);
}
__device__ __forceinline__ half8 ld_frag(const u16* p) {
    int4 v = *(const int4*)p;
    return __builtin_bit_cast(half8, v);
}
__device__ __forceinline__ short8 ld_bfrag(const u16* p) {
    int4 v = *(const int4*)p;
    return __builtin_bit_cast(short8, v);
}
__device__ __forceinline__ u32 pkrtz(float a, float b) {
    return __builtin_bit_cast(u32, __builtin_amdgcn_cvt_pkrtz(a, b));
}
__device__ __forceinline__ u16 f16b(float x) {
    _Float16 h = (_Float16)x;
    return __builtin_bit_cast(u16, h);
}
__device__ __forceinline__ float f16f(u16 v) {
    return (float)__builtin_bit_cast(_Float16, v);
}

// ---------------------------------------------------------------------------
// wpack: W (256x256 f32) -> bf16 hi/lo in A-FRAG-MAJOR layout:
//   Wf[(c>>3)*256*8 + o*8 + (c&7)] = W[o][c]
// so a conv A-frag load (lane ln -> o0+ln, k-chunk kc) is ONE coalesced 16B
// read at ((kc>>3)*256 + o)*8 — no more 64-line row gathers.
// grid (64, 4 slots = W1,W2,W3,W4), 256 thr, 4 elem/thr.
// ---------------------------------------------------------------------------
__global__ __launch_bounds__(256) void wpack(
    const float* __restrict__ W1, const float* __restrict__ W2,
    const float* __restrict__ W3, const float* __restrict__ W4,
    u16* __restrict__ Whi, u16* __restrict__ Wlo)
{
    const int slot = blockIdx.y;
    const float* W = slot == 0 ? W1 : slot == 1 ? W2 : slot == 2 ? W3 : W4;
    const int i = (blockIdx.x * 256 + threadIdx.x) * 4;
    const int o = i >> 8, c0 = i & 255;
    const f32x4 v = *(const f32x4*)(W + i);
    ushort4 h4, l4;
    h4.x = bf16rne(v.x); l4.x = bf16rne(v.x - __uint_as_float((u32)h4.x << 16));
    h4.y = bf16rne(v.y); l4.y = bf16rne(v.y - __uint_as_float((u32)h4.y << 16));
    h4.z = bf16rne(v.z); l4.z = bf16rne(v.z - __uint_as_float((u32)h4.z << 16));
    h4.w = bf16rne(v.w); l4.w = bf16rne(v.w - __uint_as_float((u32)h4.w << 16));
    const int fi = ((c0 >> 3) * 256 + o) * 8 + (c0 & 7);
    *(ushort4*)(Whi + slot * 65536 + fi) = h4;
    *(ushort4*)(Wlo + slot * 65536 + fi) = l4;
}

// ---------------------------------------------------------------------------
// conv_qkv: unified K/Q/V projection MFMA GEMM (bf16 hi/lo, 3 products).
// Block 256 thr / 4 waves; tile = 256 o x 32 s; X staged once in LDS [s][c]
// bf16 hi/lo XOR-swizzled. A-frags (W) now coalesced frag-major streams.
// grid: (128 s-tiles, 3 proj, 2 b) = 768 blocks.
// ---------------------------------------------------------------------------
__global__ __launch_bounds__(256) void conv_qkv(
    const float* __restrict__ in1, const float* __restrict__ in2,
    const u16* __restrict__ Wpk_hi, const u16* __restrict__ Wpk_lo,
    const float* __restrict__ b1, const float* __restrict__ b2,
    const float* __restrict__ b3,
    u16* __restrict__ Khi, u16* __restrict__ Klo,
    u16* __restrict__ Qpk, u16* __restrict__ Vpk)
{
    __shared__ __align__(16) u16 Xhi[32 * 256];   // 16 KB, swizzled [s][c]
    __shared__ __align__(16) u16 Xlo[32 * 256];   // 16 KB

    const int tid = threadIdx.x;
    const int w = tid >> 6, l = tid & 63;
    const int h = l >> 5, ln = l & 31;
    const int st = blockIdx.x;           // 0..127
    const int proj = blockIdx.y;         // 0 K, 1 Q, 2 V
    const int b = blockIdx.z;
    const int s0 = st * 32;

    const float* x = (proj == 2) ? in2 : in1;
    const u16* Wh = Wpk_hi + proj * 65536;
    const u16* Wl = Wpk_lo + proj * 65536;
    const float* bias = proj == 0 ? b1 : proj == 1 ? b2 : b3;

    // ---- stage X tile: wave w covers c = w*64..w*64+63; lane: s = s0+ln ----
#pragma unroll
    for (int i = 0; i < 4; ++i) {
        const int c0 = w * 64 + (h * 4 + i) * 8;
        float xv[8];
#pragma unroll
        for (int cc = 0; cc < 8; ++cc)
            xv[cc] = x[((size_t)b * CC + c0 + cc) * NSP + s0 + ln];
        u32 hw[4], lw[4];
#pragma unroll
        for (int p2 = 0; p2 < 4; ++p2) {
            const u16 h0 = bf16rne(xv[2 * p2]);
            const u16 h1 = bf16rne(xv[2 * p2 + 1]);
            const u16 l0 = bf16rne(xv[2 * p2]     - __uint_as_float((u32)h0 << 16));
            const u16 l1 = bf16rne(xv[2 * p2 + 1] - __uint_as_float((u32)h1 << 16));
            hw[p2] = (u32)h0 | ((u32)h1 << 16);
            lw[p2] = (u32)l0 | ((u32)l1 << 16);
        }
        const int off = ((ln * 256 + c0) * 2) ^ ((ln & 7) << 4);
        *(uint4*)((char*)Xhi + off) = make_uint4(hw[0], hw[1], hw[2], hw[3]);
        *(uint4*)((char*)Xlo + off) = make_uint4(lw[0], lw[1], lw[2], lw[3]);
    }
    __syncthreads();

    f32x16 acc[2];
#pragma unroll
    for (int ti = 0; ti < 2; ++ti)
#pragma unroll
        for (int i = 0; i < 16; ++i) acc[ti][i] = 0.f;

#pragma unroll 2
    for (int kk = 0; kk < 16; ++kk) {
        const int kc = kk * 16 + h * 8;
        short8 ah[2], al[2];
#pragma unroll
        for (int ti = 0; ti < 2; ++ti) {
            const size_t fi = ((size_t)(kc >> 3) * 256 + w * 64 + ti * 32 + ln) * 8;
            ah[ti] = ld_bfrag(Wh + fi);
            al[ti] = ld_bfrag(Wl + fi);
        }
        const int off = ((ln * 256 + kc) * 2) ^ ((ln & 7) << 4);
        const short8 bh_ = *(const short8*)((const char*)Xhi + off);
        const short8 bl_ = *(const short8*)((const char*)Xlo + off);
#pragma unroll
        for (int ti = 0; ti < 2; ++ti) {
            acc[ti] = __builtin_amdgcn_mfma_f32_32x32x16_bf16(ah[ti], bh_, acc[ti], 0, 0, 0);
            acc[ti] = __builtin_amdgcn_mfma_f32_32x32x16_bf16(ah[ti], bl_, acc[ti], 0, 0, 0);
            acc[ti] = __builtin_amdgcn_mfma_f32_32x32x16_bf16(al[ti], bh_, acc[ti], 0, 0, 0);
        }
    }

    // ---- epilogue: D[row = o (reg pattern), col = s = s0+ln] ----
    const int sg = s0 + ln;
#pragma unroll
    for (int ti = 0; ti < 2; ++ti)
#pragma unroll
        for (int reg = 0; reg < 16; ++reg) {
            const int o = w * 64 + ti * 32 + (reg & 3) + 8 * (reg >> 2) + 4 * h;
            const size_t SLB = (size_t)((b * 4 + (o >> 6)) * 64 + (o & 63)) * 4096;
            const float av0 = acc[ti][reg] + bias[o];
            if (proj == 2) {
                const size_t ui = SLB + (size_t)((sg >> 9) * 64 + (sg & 63)) * 8 + ((sg >> 6) & 7);
                Vpk[ui] = f16b(av0);
            } else {
                const float av = (proj == 0) ? av0 * L2E : av0;
                const _Float16 hf = (_Float16)av;
                const size_t ui = SLB + (size_t)(((sg >> 3) & 7) * 64 + (sg >> 6)) * 8 + (sg & 7);
                if (proj == 0) {
                    Khi[ui] = __builtin_bit_cast(u16, hf);
                    Klo[ui] = f16b(av - (float)hf);
                } else {
                    Qpk[ui] = __builtin_bit_cast(u16, hf);
                }
            }
        }
}

// ---------------------------------------------------------------------------
// flash3 (rt=1): each wave owns 32 K-rows (half a t-slab) -> ~half the live
// registers of R9's version (kf 32, oacc 32, sa 16) so 3-4 waves/SIMD fit.
// S^T = Q*K^T (32x32x16 f16, K hi/lo in regs, C-init = -48*log2e),
// P = exp2(S'), in-register P->A-frag via cvt_pkrtz + shfl_xor(32) +
// half-select, O += P*V.  Opart f16, 4 qq-partials.
// grid 1024: bh = id&7 (XCD-pinned), qq = (id>>3)&3, tp = id>>5 (t-pair);
// wave w: t = tp*2 + (w>>1), half = w&1.
// NOTE: keep launch_bounds (256,2) — (256,4) caused the R8 spill disaster;
// occupancy must come from NATURAL register pressure, not the allocator cap.
// ---------------------------------------------------------------------------
__global__ __launch_bounds__(256, 2) void flash3(
    const u16* __restrict__ Khi, const u16* __restrict__ Klo,
    const u16* __restrict__ Qpk, const u16* __restrict__ Vpk,
    u16* __restrict__ Oparth, float* __restrict__ zpart)
{
    const int tid = threadIdx.x;
    const int w = tid >> 6, l = tid & 63;
    const int h = l >> 5, ln = l & 31;
    const int id = blockIdx.x;
    const int bh = id & 7, qq = (id >> 3) & 3, tp = id >> 5;
    const int b = bh >> 2, hd = bh & 3;
    const int t = tp * 2 + (w >> 1), half = w & 1;

    const u16* Kh = Khi + (size_t)(bh * 64 + t) * 4096;
    const u16* Kl = Klo + (size_t)(bh * 64 + t) * 4096;

    half8 kf_h[4], kf_l[4];
#pragma unroll
    for (int ks = 0; ks < 4; ++ks) {
        const int cix = ((ks * 2 + h) * 64 + half * 32 + ln) * 8;
        kf_h[ks] = ld_frag(Kh + cix);
        kf_l[ks] = ld_frag(Kl + cix);
    }

    f32x16 oacc[2];
#pragma unroll
    for (int ft = 0; ft < 2; ++ft)
#pragma unroll
        for (int i = 0; i < 16; ++i) oacc[ft][i] = 0.f;
    float zacc = 0.f;

    for (int it = 0; it < 16; ++it) {
        const int tq = qq * 16 + it;
        const u16* Qt = Qpk + (size_t)(bh * 64 + tq) * 4096;
        const u16* Vt = Vpk + (size_t)(bh * 64 + tq) * 4096;
#pragma unroll
        for (int jt = 0; jt < 2; ++jt) {
            half8 qf[4];
#pragma unroll
            for (int ks = 0; ks < 4; ++ks)
                qf[ks] = ld_frag(Qt + ((ks * 2 + h) * 64 + jt * 32 + ln) * 8);

            f32x16 sa;
#pragma unroll
            for (int i = 0; i < 16; ++i) sa[i] = -SH2;
#pragma unroll
            for (int ks = 0; ks < 4; ++ks) {
                sa = __builtin_amdgcn_mfma_f32_32x32x16_f16(qf[ks], kf_h[ks], sa, 0, 0, 0);
                sa = __builtin_amdgcn_mfma_f32_32x32x16_f16(qf[ks], kf_l[ks], sa, 0, 0, 0);
            }

            half8 vf[2][2];
#pragma unroll
            for (int js = 0; js < 2; ++js)
#pragma unroll
                for (int ft = 0; ft < 2; ++ft)
                    vf[js][ft] = ld_frag(Vt + (((jt * 2 + js) * 2 + h) * 64 + ft * 32 + ln) * 8);

            float p[16]; float zs = 0.f;
#pragma unroll
            for (int i = 0; i < 16; ++i) { p[i] = exp2f(sa[i]); zs += p[i]; }
            zacc += zs;
            u32 wd[8], sw[8];
#pragma unroll
            for (int i = 0; i < 8; ++i) wd[i] = pkrtz(p[2 * i], p[2 * i + 1]);
#pragma unroll
            for (int i = 0; i < 8; ++i) sw[i] = (u32)__shfl_xor((int)wd[i], 32);
            int4 c0 = make_int4((int)(h ? sw[2] : wd[0]), (int)(h ? sw[3] : wd[1]),
                                (int)(h ? wd[2] : sw[0]), (int)(h ? wd[3] : sw[1]));
            int4 c1 = make_int4((int)(h ? sw[6] : wd[4]), (int)(h ? sw[7] : wd[5]),
                                (int)(h ? wd[6] : sw[4]), (int)(h ? wd[7] : sw[5]));
            const half8 pf0 = __builtin_bit_cast(half8, c0);
            const half8 pf1 = __builtin_bit_cast(half8, c1);
            oacc[0] = __builtin_amdgcn_mfma_f32_32x32x16_f16(pf0, vf[0][0], oacc[0], 0, 0, 0);
            oacc[0] = __builtin_amdgcn_mfma_f32_32x32x16_f16(pf1, vf[1][0], oacc[0], 0, 0, 0);
            oacc[1] = __builtin_amdgcn_mfma_f32_32x32x16_f16(pf0, vf[0][1], oacc[1], 0, 0, 0);
            oacc[1] = __builtin_amdgcn_mfma_f32_32x32x16_f16(pf1, vf[1][1], oacc[1], 0, 0, 0);
        }
    }

    {
        const float z2 = zacc + __shfl_xor(zacc, 32);
        if (h == 0)
            zpart[((size_t)qq * 8 + bh) * NSP + t * 64 + half * 32 + ln] = z2;
    }
    const size_t ob = ((size_t)(qq * 2 + b) * CC + hd * 64 + t) * NSP;
#pragma unroll
    for (int ft = 0; ft < 2; ++ft)
#pragma unroll
        for (int reg = 0; reg < 16; ++reg) {
            const int rin = (reg & 3) + 8 * (reg >> 2) + 4 * h;
            Oparth[ob + (size_t)(half * 32 + rin) * 64 + ft * 32 + ln]
                = f16b(oacc[ft][reg]);
        }
}

// ---------------------------------------------------------------------------
__global__ __launch_bounds__(256) void reduce_kernel(
    const float* __restrict__ zp, float* __restrict__ coef)
{
    __shared__ float red[256];
    const int tid = threadIdx.x, bh = blockIdx.x;
    float lz = 0.f;
    for (int i = tid; i < 4 * NSP; i += 256) {
        const int qq = i >> 12, r = i & 4095;
        lz += zp[((size_t)qq * 8 + bh) * NSP + r];
    }
    red[tid] = lz; __syncthreads();
    for (int s = 128; s > 0; s >>= 1) {
        if (tid < s) red[tid] += red[tid + s];
        __syncthreads();
    }
    if (tid == 0) coef[bh] = 1.f / red[0];
}

// ---------------------------------------------------------------------------
// conv_out: out = W4 . (sum of 4 f16 partials * coef) + b4, f32, MFMA.
// Block 256 thr / 4 waves; tile = 128 o (oh half) x 32 s; grid (128,2,2)=512.
// W4 A-frags coalesced frag-major.
// ---------------------------------------------------------------------------
__global__ __launch_bounds__(256) void conv_out(
    const u16* __restrict__ Oparth,
    const u16* __restrict__ Wpk_hi, const u16* __restrict__ Wpk_lo,
    const float* __restrict__ b4, const float* __restrict__ coef,
    float* __restrict__ out)
{
    __shared__ __align__(16) u16 Xhi[32 * 256];   // 16 KB
    __shared__ __align__(16) u16 Xlo[32 * 256];   // 16 KB

    const int tid = threadIdx.x;
    const int w = tid >> 6, l = tid & 63;
    const int h = l >> 5, ln = l & 31;
    const int st = blockIdx.x;           // 0..127
    const int oh = blockIdx.y;           // o half
    const int b = blockIdx.z;
    const int s0 = st * 32;

    const u16* Wh = Wpk_hi + 3 * 65536;
    const u16* Wl = Wpk_lo + 3 * 65536;
    const size_t TENu = (size_t)2 * CC * NSP;

    // ---- stage: sum 4 f16 partials * coef -> bf16 hi/lo LDS ----
    const float cf = coef[b * 4 + w];
#pragma unroll
    for (int i = 0; i < 4; ++i) {
        const int c0 = w * 64 + (h * 4 + i) * 8;
        float xv[8];
#pragma unroll
        for (int cc = 0; cc < 8; ++cc) {
            const size_t base = ((size_t)b * CC + c0 + cc) * NSP + s0 + ln;
            float s = 0.f;
#pragma unroll
            for (int pp = 0; pp < 4; ++pp)
                s += f16f(Oparth[pp * TENu + base]);
            xv[cc] = s * cf;
        }
        u32 hw[4], lw[4];
#pragma unroll
        for (int p2 = 0; p2 < 4; ++p2) {
            const u16 h0 = bf16rne(xv[2 * p2]);
            const u16 h1 = bf16rne(xv[2 * p2 + 1]);
            const u16 l0 = bf16rne(xv[2 * p2]     - __uint_as_float((u32)h0 << 16));
            const u16 l1 = bf16rne(xv[2 * p2 + 1] - __uint_as_float((u32)h1 << 16));
            hw[p2] = (u32)h0 | ((u32)h1 << 16);
            lw[p2] = (u32)l0 | ((u32)l1 << 16);
        }
        const int off = ((ln * 256 + c0) * 2) ^ ((ln & 7) << 4);
        *(uint4*)((char*)Xhi + off) = make_uint4(hw[0], hw[1], hw[2], hw[3]);
        *(uint4*)((char*)Xlo + off) = make_uint4(lw[0], lw[1], lw[2], lw[3]);
    }
    __syncthreads();

    f32x16 acc;
#pragma unroll
    for (int i = 0; i < 16; ++i) acc[i] = 0.f;

#pragma unroll 2
    for (int kk = 0; kk < 16; ++kk) {
        const int kc = kk * 16 + h * 8;
        const size_t fi = ((size_t)(kc >> 3) * 256 + oh * 128 + w * 32 + ln) * 8;
        const short8 ah = ld_bfrag(Wh + fi);
        const short8 al = ld_bfrag(Wl + fi);
        const int off = ((ln * 256 + kc) * 2) ^ ((ln & 7) << 4);
        const short8 bh_ = *(const short8*)((const char*)Xhi + off);
        const short8 bl_ = *(const short8*)((const char*)Xlo + off);
        acc = __builtin_amdgcn_mfma_f32_32x32x16_bf16(ah, bh_, acc, 0, 0, 0);
        acc = __builtin_amdgcn_mfma_f32_32x32x16_bf16(ah, bl_, acc, 0, 0, 0);
        acc = __builtin_amdgcn_mfma_f32_32x32x16_bf16(al, bh_, acc, 0, 0, 0);
    }

    const int sg = s0 + ln;
#pragma unroll
    for (int reg = 0; reg < 16; ++reg) {
        const int o = oh * 128 + w * 32 + (reg & 3) + 8 * (reg >> 2) + 4 * h;
        out[((size_t)b * CC + o) * NSP + sg] = acc[reg] + b4[o];
    }
}

// ---------------------------------------------------------------------------
extern "C" void kernel_launch(void* const* d_in, const int* in_sizes, int n_in,
                              void* d_out, int out_size, void* d_ws, size_t ws_size,
                              hipStream_t stream)
{
    (void)in_sizes; (void)n_in; (void)out_size; (void)ws_size;
    const float* in1 = (const float*)d_in[0];
    const float* in2 = (const float*)d_in[1];
    const float* W1 = (const float*)d_in[2]; const float* b1 = (const float*)d_in[3];
    const float* W2 = (const float*)d_in[4]; const float* b2 = (const float*)d_in[5];
    const float* W3 = (const float*)d_in[6]; const float* b3 = (const float*)d_in[7];
    const float* W4 = (const float*)d_in[8]; const float* b4 = (const float*)d_in[9];
    float* out = (float*)d_out;

    const size_t TEN = (size_t)2 * CC * NSP;          // 2,097,152 elements
    char* p = (char*)d_ws;
    u16* Khi = (u16*)p; p += TEN * 2;                 // 4 MB each
    u16* Klo = (u16*)p; p += TEN * 2;
    u16* Qpk = (u16*)p; p += TEN * 2;
    u16* Vpk = (u16*)p; p += TEN * 2;
    u16* Wph = (u16*)p; p += 4 * 65536 * 2;           // 512 KB
    u16* Wpl = (u16*)p; p += 4 * 65536 * 2;           // 512 KB
    u16* Oparth = (u16*)p; p += 4 * TEN * 2;          // 16 MB (4 f16 partials)
    float* zpart = (float*)p; p += (size_t)4 * 8 * NSP * 4;   // 0.5 MB
    float* coef  = (float*)p;

    wpack<<<dim3(64, 4), 256, 0, stream>>>(W1, W2, W3, W4, Wph, Wpl);
    conv_qkv<<<dim3(128, 3, 2), 256, 0, stream>>>(
        in1, in2, Wph, Wpl, b1, b2, b3, Khi, Klo, Qpk, Vpk);
    flash3<<<dim3(1024), 256, 0, stream>>>(Khi, Klo, Qpk, Vpk, Oparth, zpart);
    reduce_kernel<<<dim3(8), 256, 0, stream>>>(zpart, coef);
    conv_out<<<dim3(128, 2, 2), 256, 0, stream>>>(Oparth, Wph, Wpl, b4, coef, out);
}

// Round 11
// 146.106 us; speedup vs baseline: 4.5789x; 1.0618x over previous
//
#include <hip/hip_runtime.h>
#include <math.h>

#define CC 256
#define NSP 4096
#define L2E 1.44269504088896340736f
#define SH2 (48.0f * L2E)

typedef float f32x4  __attribute__((ext_vector_type(4)));
typedef float f32x16 __attribute__((ext_vector_type(16)));
typedef _Float16 half8 __attribute__((ext_vector_type(8)));
typedef short short8 __attribute__((ext_vector_type(8)));
typedef unsigned short u16;
typedef unsigned int   u32;

__device__ __forceinline__ u16 bf16rne(float x) {
    unsigned u = __float_as_uint(x);
    u += 0x7FFFu + ((u >> 16) & 1u);
    return (u16)(u >> 16);
}
__device__ __forceinline__ half8 ld_frag(const u16* p) {
    int4 v = *(const int4*)p;
    return __builtin_bit_cast(half8, v);
}
__device__ __forceinline__ short8 ld_bfrag(const u16* p) {
    int4 v = *(const int4*)p;
    return __builtin_bit_cast(short8, v);
}
__device__ __forceinline__ u32 pkrtz(float a, float b) {
    return __builtin_bit_cast(u32, __builtin_amdgcn_cvt_pkrtz(a, b));
}
__device__ __forceinline__ u16 f16b(float x) {
    _Float16 h = (_Float16)x;
    return __builtin_bit_cast(u16, h);
}
__device__ __forceinline__ float f16f(u16 v) {
    return (float)__builtin_bit_cast(_Float16, v);
}

// ---------------------------------------------------------------------------
// wpack: W (256x256 f32) -> bf16 hi/lo in A-FRAG-MAJOR layout:
//   Wf[(c>>3)*256*8 + o*8 + (c&7)] = W[o][c]
// so a conv A-frag load (lane ln -> o, k-chunk kc) is ONE coalesced 16B read.
// grid (64, 4 slots = W1,W2,W3,W4), 256 thr, 4 elem/thr.
// ---------------------------------------------------------------------------
__global__ __launch_bounds__(256) void wpack(
    const float* __restrict__ W1, const float* __restrict__ W2,
    const float* __restrict__ W3, const float* __restrict__ W4,
    u16* __restrict__ Whi, u16* __restrict__ Wlo)
{
    const int slot = blockIdx.y;
    const float* W = slot == 0 ? W1 : slot == 1 ? W2 : slot == 2 ? W3 : W4;
    const int i = (blockIdx.x * 256 + threadIdx.x) * 4;
    const int o = i >> 8, c0 = i & 255;
    const f32x4 v = *(const f32x4*)(W + i);
    ushort4 h4, l4;
    h4.x = bf16rne(v.x); l4.x = bf16rne(v.x - __uint_as_float((u32)h4.x << 16));
    h4.y = bf16rne(v.y); l4.y = bf16rne(v.y - __uint_as_float((u32)h4.y << 16));
    h4.z = bf16rne(v.z); l4.z = bf16rne(v.z - __uint_as_float((u32)h4.z << 16));
    h4.w = bf16rne(v.w); l4.w = bf16rne(v.w - __uint_as_float((u32)h4.w << 16));
    const int fi = ((c0 >> 3) * 256 + o) * 8 + (c0 & 7);
    *(ushort4*)(Whi + slot * 65536 + fi) = h4;
    *(ushort4*)(Wlo + slot * 65536 + fi) = l4;
}

// ---------------------------------------------------------------------------
// conv_qkv: unified K/Q/V projection MFMA GEMM (bf16 hi/lo, 3 products).
// Block 256 thr / 4 waves; tile = 256 o x 32 s; X staged once in LDS [s][c]
// bf16 hi/lo XOR-swizzled. A-frags (W) coalesced frag-major streams.
// grid: (128 s-tiles, 3 proj, 2 b) = 768 blocks.
// ---------------------------------------------------------------------------
__global__ __launch_bounds__(256) void conv_qkv(
    const float* __restrict__ in1, const float* __restrict__ in2,
    const u16* __restrict__ Wpk_hi, const u16* __restrict__ Wpk_lo,
    const float* __restrict__ b1, const float* __restrict__ b2,
    const float* __restrict__ b3,
    u16* __restrict__ Khi, u16* __restrict__ Klo,
    u16* __restrict__ Qpk, u16* __restrict__ Vpk)
{
    __shared__ __align__(16) u16 Xhi[32 * 256];   // 16 KB, swizzled [s][c]
    __shared__ __align__(16) u16 Xlo[32 * 256];   // 16 KB

    const int tid = threadIdx.x;
    const int w = tid >> 6, l = tid & 63;
    const int h = l >> 5, ln = l & 31;
    const int st = blockIdx.x;           // 0..127
    const int proj = blockIdx.y;         // 0 K, 1 Q, 2 V
    const int b = blockIdx.z;
    const int s0 = st * 32;

    const float* x = (proj == 2) ? in2 : in1;
    const u16* Wh = Wpk_hi + proj * 65536;
    const u16* Wl = Wpk_lo + proj * 65536;
    const float* bias = proj == 0 ? b1 : proj == 1 ? b2 : b3;

    // ---- stage X tile: wave w covers c = w*64..w*64+63; lane: s = s0+ln ----
#pragma unroll
    for (int i = 0; i < 4; ++i) {
        const int c0 = w * 64 + (h * 4 + i) * 8;
        float xv[8];
#pragma unroll
        for (int cc = 0; cc < 8; ++cc)
            xv[cc] = x[((size_t)b * CC + c0 + cc) * NSP + s0 + ln];
        u32 hw[4], lw[4];
#pragma unroll
        for (int p2 = 0; p2 < 4; ++p2) {
            const u16 h0 = bf16rne(xv[2 * p2]);
            const u16 h1 = bf16rne(xv[2 * p2 + 1]);
            const u16 l0 = bf16rne(xv[2 * p2]     - __uint_as_float((u32)h0 << 16));
            const u16 l1 = bf16rne(xv[2 * p2 + 1] - __uint_as_float((u32)h1 << 16));
            hw[p2] = (u32)h0 | ((u32)h1 << 16);
            lw[p2] = (u32)l0 | ((u32)l1 << 16);
        }
        const int off = ((ln * 256 + c0) * 2) ^ ((ln & 7) << 4);
        *(uint4*)((char*)Xhi + off) = make_uint4(hw[0], hw[1], hw[2], hw[3]);
        *(uint4*)((char*)Xlo + off) = make_uint4(lw[0], lw[1], lw[2], lw[3]);
    }
    __syncthreads();

    f32x16 acc[2];
#pragma unroll
    for (int ti = 0; ti < 2; ++ti)
#pragma unroll
        for (int i = 0; i < 16; ++i) acc[ti][i] = 0.f;

#pragma unroll 2
    for (int kk = 0; kk < 16; ++kk) {
        const int kc = kk * 16 + h * 8;
        short8 ah[2], al[2];
#pragma unroll
        for (int ti = 0; ti < 2; ++ti) {
            const size_t fi = ((size_t)(kc >> 3) * 256 + w * 64 + ti * 32 + ln) * 8;
            ah[ti] = ld_bfrag(Wh + fi);
            al[ti] = ld_bfrag(Wl + fi);
        }
        const int off = ((ln * 256 + kc) * 2) ^ ((ln & 7) << 4);
        const short8 bh_ = *(const short8*)((const char*)Xhi + off);
        const short8 bl_ = *(const short8*)((const char*)Xlo + off);
#pragma unroll
        for (int ti = 0; ti < 2; ++ti) {
            acc[ti] = __builtin_amdgcn_mfma_f32_32x32x16_bf16(ah[ti], bh_, acc[ti], 0, 0, 0);
            acc[ti] = __builtin_amdgcn_mfma_f32_32x32x16_bf16(ah[ti], bl_, acc[ti], 0, 0, 0);
            acc[ti] = __builtin_amdgcn_mfma_f32_32x32x16_bf16(al[ti], bh_, acc[ti], 0, 0, 0);
        }
    }

    // ---- epilogue: D[row = o (reg pattern), col = s = s0+ln] ----
    const int sg = s0 + ln;
#pragma unroll
    for (int ti = 0; ti < 2; ++ti)
#pragma unroll
        for (int reg = 0; reg < 16; ++reg) {
            const int o = w * 64 + ti * 32 + (reg & 3) + 8 * (reg >> 2) + 4 * h;
            const size_t SLB = (size_t)((b * 4 + (o >> 6)) * 64 + (o & 63)) * 4096;
            const float av0 = acc[ti][reg] + bias[o];
            if (proj == 2) {
                const size_t ui = SLB + (size_t)((sg >> 9) * 64 + (sg & 63)) * 8 + ((sg >> 6) & 7);
                Vpk[ui] = f16b(av0);
            } else {
                const float av = (proj == 0) ? av0 * L2E : av0;
                const _Float16 hf = (_Float16)av;
                const size_t ui = SLB + (size_t)(((sg >> 3) & 7) * 64 + (sg >> 6)) * 8 + (sg & 7);
                if (proj == 0) {
                    Khi[ui] = __builtin_bit_cast(u16, hf);
                    Klo[ui] = f16b(av - (float)hf);
                } else {
                    Qpk[ui] = __builtin_bit_cast(u16, hf);
                }
            }
        }
}

// ---------------------------------------------------------------------------
// flash3 (rt=2, R9 structure — 2 independent MFMA chains + 2x fragment reuse;
// R10's rt=1 doubled Q/V load traffic and lost ILP, 79->91 µs regression):
// S^T = Q*K^T (32x32x16 f16, K hi/lo in regs, C-init = -48*log2e),
// P = exp2(S') via __builtin_amdgcn_exp2f (single v_exp_f32 — plain exp2f
// may lower to an OCML libcall without fast-math), in-register P->A-frag via
// cvt_pkrtz + shfl_xor(32) + half-select, O += P*V. s_setprio(1) around the
// MFMA clusters (T5: no barriers here, waves drift out of phase).
// Opart f16, 8 qq-partials. grid 1024: bh = id&7, qq = (id>>3)&7, tb = id>>6.
// NOTE: keep launch_bounds (256,2) — (256,4) caused the R8 spill disaster.
// ---------------------------------------------------------------------------
__global__ __launch_bounds__(256, 2) void flash3(
    const u16* __restrict__ Khi, const u16* __restrict__ Klo,
    const u16* __restrict__ Qpk, const u16* __restrict__ Vpk,
    u16* __restrict__ Oparth, float* __restrict__ zpart)
{
    const int tid = threadIdx.x;
    const int w = tid >> 6, l = tid & 63;
    const int h = l >> 5, ln = l & 31;
    const int id = blockIdx.x;
    const int bh = id & 7, qq = (id >> 3) & 7, tb = id >> 6;
    const int b = bh >> 2, hd = bh & 3;
    const int t = tb * 4 + w;

    const u16* Kh = Khi + (size_t)(bh * 64 + t) * 4096;
    const u16* Kl = Klo + (size_t)(bh * 64 + t) * 4096;

    half8 kf_h[2][4], kf_l[2][4];
#pragma unroll
    for (int rt = 0; rt < 2; ++rt)
#pragma unroll
        for (int ks = 0; ks < 4; ++ks) {
            const int cix = ((ks * 2 + h) * 64 + rt * 32 + ln) * 8;
            kf_h[rt][ks] = ld_frag(Kh + cix);
            kf_l[rt][ks] = ld_frag(Kl + cix);
        }

    f32x16 oacc[2][2];
#pragma unroll
    for (int rt = 0; rt < 2; ++rt)
#pragma unroll
        for (int ft = 0; ft < 2; ++ft)
#pragma unroll
            for (int i = 0; i < 16; ++i) oacc[rt][ft][i] = 0.f;
    float zacc[2] = {0.f, 0.f};

    for (int it = 0; it < 8; ++it) {
        const int tq = qq * 8 + it;
        const u16* Qt = Qpk + (size_t)(bh * 64 + tq) * 4096;
        const u16* Vt = Vpk + (size_t)(bh * 64 + tq) * 4096;
#pragma unroll
        for (int jt = 0; jt < 2; ++jt) {
            half8 qf[4];
#pragma unroll
            for (int ks = 0; ks < 4; ++ks)
                qf[ks] = ld_frag(Qt + ((ks * 2 + h) * 64 + jt * 32 + ln) * 8);

            f32x16 sa[2];
#pragma unroll
            for (int rt = 0; rt < 2; ++rt)
#pragma unroll
                for (int i = 0; i < 16; ++i) sa[rt][i] = -SH2;
            __builtin_amdgcn_s_setprio(1);
#pragma unroll
            for (int ks = 0; ks < 4; ++ks) {
                sa[0] = __builtin_amdgcn_mfma_f32_32x32x16_f16(qf[ks], kf_h[0][ks], sa[0], 0, 0, 0);
                sa[1] = __builtin_amdgcn_mfma_f32_32x32x16_f16(qf[ks], kf_h[1][ks], sa[1], 0, 0, 0);
                sa[0] = __builtin_amdgcn_mfma_f32_32x32x16_f16(qf[ks], kf_l[0][ks], sa[0], 0, 0, 0);
                sa[1] = __builtin_amdgcn_mfma_f32_32x32x16_f16(qf[ks], kf_l[1][ks], sa[1], 0, 0, 0);
            }
            __builtin_amdgcn_s_setprio(0);

            half8 vf[2][2];
#pragma unroll
            for (int js = 0; js < 2; ++js)
#pragma unroll
                for (int ft = 0; ft < 2; ++ft)
                    vf[js][ft] = ld_frag(Vt + (((jt * 2 + js) * 2 + h) * 64 + ft * 32 + ln) * 8);

#pragma unroll
            for (int rt = 0; rt < 2; ++rt) {
                float p[16]; float zs = 0.f;
#pragma unroll
                for (int i = 0; i < 16; ++i) {
                    p[i] = __builtin_amdgcn_exp2f(sa[rt][i]);
                    zs += p[i];
                }
                zacc[rt] += zs;
                u32 wd[8], sw[8];
#pragma unroll
                for (int i = 0; i < 8; ++i) wd[i] = pkrtz(p[2 * i], p[2 * i + 1]);
#pragma unroll
                for (int i = 0; i < 8; ++i) sw[i] = (u32)__shfl_xor((int)wd[i], 32);
                int4 c0 = make_int4((int)(h ? sw[2] : wd[0]), (int)(h ? sw[3] : wd[1]),
                                    (int)(h ? wd[2] : sw[0]), (int)(h ? wd[3] : sw[1]));
                int4 c1 = make_int4((int)(h ? sw[6] : wd[4]), (int)(h ? sw[7] : wd[5]),
                                    (int)(h ? wd[6] : sw[4]), (int)(h ? wd[7] : sw[5]));
                const half8 pf0 = __builtin_bit_cast(half8, c0);
                const half8 pf1 = __builtin_bit_cast(half8, c1);
                __builtin_amdgcn_s_setprio(1);
                oacc[rt][0] = __builtin_amdgcn_mfma_f32_32x32x16_f16(pf0, vf[0][0], oacc[rt][0], 0, 0, 0);
                oacc[rt][0] = __builtin_amdgcn_mfma_f32_32x32x16_f16(pf1, vf[1][0], oacc[rt][0], 0, 0, 0);
                oacc[rt][1] = __builtin_amdgcn_mfma_f32_32x32x16_f16(pf0, vf[0][1], oacc[rt][1], 0, 0, 0);
                oacc[rt][1] = __builtin_amdgcn_mfma_f32_32x32x16_f16(pf1, vf[1][1], oacc[rt][1], 0, 0, 0);
                __builtin_amdgcn_s_setprio(0);
            }
        }
    }

#pragma unroll
    for (int rt = 0; rt < 2; ++rt) {
        const float z2 = zacc[rt] + __shfl_xor(zacc[rt], 32);
        if (h == 0)
            zpart[((size_t)qq * 8 + bh) * NSP + t * 64 + rt * 32 + ln] = z2;
    }
    const size_t ob = ((size_t)(qq * 2 + b) * CC + hd * 64 + t) * NSP;
#pragma unroll
    for (int rt = 0; rt < 2; ++rt)
#pragma unroll
        for (int ft = 0; ft < 2; ++ft)
#pragma unroll
            for (int reg = 0; reg < 16; ++reg) {
                const int rin = (reg & 3) + 8 * (reg >> 2) + 4 * h;
                Oparth[ob + (size_t)(rt * 32 + rin) * 64 + ft * 32 + ln]
                    = f16b(oacc[rt][ft][reg]);
            }
}

// ---------------------------------------------------------------------------
__global__ __launch_bounds__(256) void reduce_kernel(
    const float* __restrict__ zp, float* __restrict__ coef)
{
    __shared__ float red[256];
    const int tid = threadIdx.x, bh = blockIdx.x;
    float lz = 0.f;
    for (int i = tid; i < 8 * NSP; i += 256) {
        const int qq = i >> 12, r = i & 4095;
        lz += zp[((size_t)qq * 8 + bh) * NSP + r];
    }
    red[tid] = lz; __syncthreads();
    for (int s = 128; s > 0; s >>= 1) {
        if (tid < s) red[tid] += red[tid + s];
        __syncthreads();
    }
    if (tid == 0) coef[bh] = 1.f / red[0];
}

// ---------------------------------------------------------------------------
// conv_out: out = W4 . (sum of 8 f16 partials * coef) + b4, f32, MFMA.
// Block 256 thr / 4 waves; tile = 128 o (oh half) x 32 s; grid (128,2,2)=512.
// W4 A-frags coalesced frag-major.
// ---------------------------------------------------------------------------
__global__ __launch_bounds__(256) void conv_out(
    const u16* __restrict__ Oparth,
    const u16* __restrict__ Wpk_hi, const u16* __restrict__ Wpk_lo,
    const float* __restrict__ b4, const float* __restrict__ coef,
    float* __restrict__ out)
{
    __shared__ __align__(16) u16 Xhi[32 * 256];   // 16 KB
    __shared__ __align__(16) u16 Xlo[32 * 256];   // 16 KB

    const int tid = threadIdx.x;
    const int w = tid >> 6, l = tid & 63;
    const int h = l >> 5, ln = l & 31;
    const int st = blockIdx.x;           // 0..127
    const int oh = blockIdx.y;           // o half
    const int b = blockIdx.z;
    const int s0 = st * 32;

    const u16* Wh = Wpk_hi + 3 * 65536;
    const u16* Wl = Wpk_lo + 3 * 65536;
    const size_t TENu = (size_t)2 * CC * NSP;

    // ---- stage: sum 8 f16 partials * coef -> bf16 hi/lo LDS ----
    const float cf = coef[b * 4 + w];
#pragma unroll
    for (int i = 0; i < 4; ++i) {
        const int c0 = w * 64 + (h * 4 + i) * 8;
        float xv[8];
#pragma unroll
        for (int cc = 0; cc < 8; ++cc) {
            const size_t base = ((size_t)b * CC + c0 + cc) * NSP + s0 + ln;
            float s = 0.f;
#pragma unroll
            for (int pp = 0; pp < 8; ++pp)
                s += f16f(Oparth[pp * TENu + base]);
            xv[cc] = s * cf;
        }
        u32 hw[4], lw[4];
#pragma unroll
        for (int p2 = 0; p2 < 4; ++p2) {
            const u16 h0 = bf16rne(xv[2 * p2]);
            const u16 h1 = bf16rne(xv[2 * p2 + 1]);
            const u16 l0 = bf16rne(xv[2 * p2]     - __uint_as_float((u32)h0 << 16));
            const u16 l1 = bf16rne(xv[2 * p2 + 1] - __uint_as_float((u32)h1 << 16));
            hw[p2] = (u32)h0 | ((u32)h1 << 16);
            lw[p2] = (u32)l0 | ((u32)l1 << 16);
        }
        const int off = ((ln * 256 + c0) * 2) ^ ((ln & 7) << 4);
        *(uint4*)((char*)Xhi + off) = make_uint4(hw[0], hw[1], hw[2], hw[3]);
        *(uint4*)((char*)Xlo + off) = make_uint4(lw[0], lw[1], lw[2], lw[3]);
    }
    __syncthreads();

    f32x16 acc;
#pragma unroll
    for (int i = 0; i < 16; ++i) acc[i] = 0.f;

#pragma unroll 2
    for (int kk = 0; kk < 16; ++kk) {
        const int kc = kk * 16 + h * 8;
        const size_t fi = ((size_t)(kc >> 3) * 256 + oh * 128 + w * 32 + ln) * 8;
        const short8 ah = ld_bfrag(Wh + fi);
        const short8 al = ld_bfrag(Wl + fi);
        const int off = ((ln * 256 + kc) * 2) ^ ((ln & 7) << 4);
        const short8 bh_ = *(const short8*)((const char*)Xhi + off);
        const short8 bl_ = *(const short8*)((const char*)Xlo + off);
        acc = __builtin_amdgcn_mfma_f32_32x32x16_bf16(ah, bh_, acc, 0, 0, 0);
        acc = __builtin_amdgcn_mfma_f32_32x32x16_bf16(ah, bl_, acc, 0, 0, 0);
        acc = __builtin_amdgcn_mfma_f32_32x32x16_bf16(al, bh_, acc, 0, 0, 0);
    }

    const int sg = s0 + ln;
#pragma unroll
    for (int reg = 0; reg < 16; ++reg) {
        const int o = oh * 128 + w * 32 + (reg & 3) + 8 * (reg >> 2) + 4 * h;
        out[((size_t)b * CC + o) * NSP + sg] = acc[reg] + b4[o];
    }
}

// ---------------------------------------------------------------------------
extern "C" void kernel_launch(void* const* d_in, const int* in_sizes, int n_in,
                              void* d_out, int out_size, void* d_ws, size_t ws_size,
                              hipStream_t stream)
{
    (void)in_sizes; (void)n_in; (void)out_size; (void)ws_size;
    const float* in1 = (const float*)d_in[0];
    const float* in2 = (const float*)d_in[1];
    const float* W1 = (const float*)d_in[2]; const float* b1 = (const float*)d_in[3];
    const float* W2 = (const float*)d_in[4]; const float* b2 = (const float*)d_in[5];
    const float* W3 = (const float*)d_in[6]; const float* b3 = (const float*)d_in[7];
    const float* W4 = (const float*)d_in[8]; const float* b4 = (const float*)d_in[9];
    float* out = (float*)d_out;

    const size_t TEN = (size_t)2 * CC * NSP;          // 2,097,152 elements
    char* p = (char*)d_ws;
    u16* Khi = (u16*)p; p += TEN * 2;                 // 4 MB each
    u16* Klo = (u16*)p; p += TEN * 2;
    u16* Qpk = (u16*)p; p += TEN * 2;
    u16* Vpk = (u16*)p; p += TEN * 2;
    u16* Wph = (u16*)p; p += 4 * 65536 * 2;           // 512 KB
    u16* Wpl = (u16*)p; p += 4 * 65536 * 2;           // 512 KB
    u16* Oparth = (u16*)p; p += 8 * TEN * 2;          // 32 MB (8 f16 partials)
    float* zpart = (float*)p; p += (size_t)8 * 8 * NSP * 4;   // 1 MB
    float* coef  = (float*)p;

    wpack<<<dim3(64, 4), 256, 0, stream>>>(W1, W2, W3, W4, Wph, Wpl);
    conv_qkv<<<dim3(128, 3, 2), 256, 0, stream>>>(
        in1, in2, Wph, Wpl, b1, b2, b3, Khi, Klo, Qpk, Vpk);
    flash3<<<dim3(1024), 256, 0, stream>>>(Khi, Klo, Qpk, Vpk, Oparth, zpart);
    reduce_kernel<<<dim3(8), 256, 0, stream>>>(zpart, coef);
    conv_out<<<dim3(128, 2, 2), 256, 0, stream>>>(Oparth, Wph, Wpl, b4, coef, out);
}

// Round 12
// 126.700 us; speedup vs baseline: 5.2803x; 1.1532x over previous
//
#include <hip/hip_runtime.h>
#include <math.h>

#define CC 256
#define NSP 4096
#define L2E 1.44269504088896340736f
#define SH2 (48.0f * L2E)

typedef float f32x4  __attribute__((ext_vector_type(4)));
typedef float f32x16 __attribute__((ext_vector_type(16)));
typedef _Float16 half8 __attribute__((ext_vector_type(8)));
typedef short short8 __attribute__((ext_vector_type(8)));
typedef unsigned short u16;
typedef unsigned int   u32;

__device__ __forceinline__ u16 bf16rne(float x) {
    unsigned u = __float_as_uint(x);
    u += 0x7FFFu + ((u >> 16) & 1u);
    return (u16)(u >> 16);
}
__device__ __forceinline__ half8 ld_frag(const u16* p) {
    int4 v = *(const int4*)p;
    return __builtin_bit_cast(half8, v);
}
__device__ __forceinline__ short8 ld_bfrag(const u16* p) {
    int4 v = *(const int4*)p;
    return __builtin_bit_cast(short8, v);
}
__device__ __forceinline__ u32 pkrtz(float a, float b) {
    return __builtin_bit_cast(u32, __builtin_amdgcn_cvt_pkrtz(a, b));
}
__device__ __forceinline__ u16 f16b(float x) {
    _Float16 h = (_Float16)x;
    return __builtin_bit_cast(u16, h);
}

// ---------------------------------------------------------------------------
// wpack: W (256x256 f32) -> bf16 hi/lo in A-FRAG-MAJOR layout:
//   Wf[(c>>3)*256*8 + o*8 + (c&7)] = W[o][c]   (one coalesced 16B/lane read)
// grid (64, 4 slots = W1,W2,W3,W4), 256 thr, 4 elem/thr.
// ---------------------------------------------------------------------------
__global__ __launch_bounds__(256) void wpack(
    const float* __restrict__ W1, const float* __restrict__ W2,
    const float* __restrict__ W3, const float* __restrict__ W4,
    u16* __restrict__ Whi, u16* __restrict__ Wlo)
{
    const int slot = blockIdx.y;
    const float* W = slot == 0 ? W1 : slot == 1 ? W2 : slot == 2 ? W3 : W4;
    const int i = (blockIdx.x * 256 + threadIdx.x) * 4;
    const int o = i >> 8, c0 = i & 255;
    const f32x4 v = *(const f32x4*)(W + i);
    ushort4 h4, l4;
    h4.x = bf16rne(v.x); l4.x = bf16rne(v.x - __uint_as_float((u32)h4.x << 16));
    h4.y = bf16rne(v.y); l4.y = bf16rne(v.y - __uint_as_float((u32)h4.y << 16));
    h4.z = bf16rne(v.z); l4.z = bf16rne(v.z - __uint_as_float((u32)h4.z << 16));
    h4.w = bf16rne(v.w); l4.w = bf16rne(v.w - __uint_as_float((u32)h4.w << 16));
    const int fi = ((c0 >> 3) * 256 + o) * 8 + (c0 & 7);
    *(ushort4*)(Whi + slot * 65536 + fi) = h4;
    *(ushort4*)(Wlo + slot * 65536 + fi) = l4;
}

// ---------------------------------------------------------------------------
// conv_qkv: unified K/Q/V projection MFMA GEMM (bf16 hi/lo, 3 products).
// Block 256 thr / 4 waves; tile = 256 o x 32 s; X staged once in LDS [s][c]
// bf16 hi/lo XOR-swizzled. A-frags (W) coalesced frag-major streams.
// K is now SINGLE f16 (xL2E) — Q-f16 rounding already dominates the score
// error, so K-lo bought nothing (R12 change; error budget 3-4e-3 vs 9.7e-3).
// grid: (128 s-tiles, 3 proj, 2 b) = 768 blocks.
// ---------------------------------------------------------------------------
__global__ __launch_bounds__(256) void conv_qkv(
    const float* __restrict__ in1, const float* __restrict__ in2,
    const u16* __restrict__ Wpk_hi, const u16* __restrict__ Wpk_lo,
    const float* __restrict__ b1, const float* __restrict__ b2,
    const float* __restrict__ b3,
    u16* __restrict__ Kpk, u16* __restrict__ Qpk, u16* __restrict__ Vpk)
{
    __shared__ __align__(16) u16 Xhi[32 * 256];   // 16 KB, swizzled [s][c]
    __shared__ __align__(16) u16 Xlo[32 * 256];   // 16 KB

    const int tid = threadIdx.x;
    const int w = tid >> 6, l = tid & 63;
    const int h = l >> 5, ln = l & 31;
    const int st = blockIdx.x;           // 0..127
    const int proj = blockIdx.y;         // 0 K, 1 Q, 2 V
    const int b = blockIdx.z;
    const int s0 = st * 32;

    const float* x = (proj == 2) ? in2 : in1;
    const u16* Wh = Wpk_hi + proj * 65536;
    const u16* Wl = Wpk_lo + proj * 65536;
    const float* bias = proj == 0 ? b1 : proj == 1 ? b2 : b3;

    // ---- stage X tile: wave w covers c = w*64..w*64+63; lane: s = s0+ln ----
#pragma unroll
    for (int i = 0; i < 4; ++i) {
        const int c0 = w * 64 + (h * 4 + i) * 8;
        float xv[8];
#pragma unroll
        for (int cc = 0; cc < 8; ++cc)
            xv[cc] = x[((size_t)b * CC + c0 + cc) * NSP + s0 + ln];
        u32 hw[4], lw[4];
#pragma unroll
        for (int p2 = 0; p2 < 4; ++p2) {
            const u16 h0 = bf16rne(xv[2 * p2]);
            const u16 h1 = bf16rne(xv[2 * p2 + 1]);
            const u16 l0 = bf16rne(xv[2 * p2]     - __uint_as_float((u32)h0 << 16));
            const u16 l1 = bf16rne(xv[2 * p2 + 1] - __uint_as_float((u32)h1 << 16));
            hw[p2] = (u32)h0 | ((u32)h1 << 16);
            lw[p2] = (u32)l0 | ((u32)l1 << 16);
        }
        const int off = ((ln * 256 + c0) * 2) ^ ((ln & 7) << 4);
        *(uint4*)((char*)Xhi + off) = make_uint4(hw[0], hw[1], hw[2], hw[3]);
        *(uint4*)((char*)Xlo + off) = make_uint4(lw[0], lw[1], lw[2], lw[3]);
    }
    __syncthreads();

    f32x16 acc[2];
#pragma unroll
    for (int ti = 0; ti < 2; ++ti)
#pragma unroll
        for (int i = 0; i < 16; ++i) acc[ti][i] = 0.f;

#pragma unroll 2
    for (int kk = 0; kk < 16; ++kk) {
        const int kc = kk * 16 + h * 8;
        short8 ah[2], al[2];
#pragma unroll
        for (int ti = 0; ti < 2; ++ti) {
            const size_t fi = ((size_t)(kc >> 3) * 256 + w * 64 + ti * 32 + ln) * 8;
            ah[ti] = ld_bfrag(Wh + fi);
            al[ti] = ld_bfrag(Wl + fi);
        }
        const int off = ((ln * 256 + kc) * 2) ^ ((ln & 7) << 4);
        const short8 bh_ = *(const short8*)((const char*)Xhi + off);
        const short8 bl_ = *(const short8*)((const char*)Xlo + off);
#pragma unroll
        for (int ti = 0; ti < 2; ++ti) {
            acc[ti] = __builtin_amdgcn_mfma_f32_32x32x16_bf16(ah[ti], bh_, acc[ti], 0, 0, 0);
            acc[ti] = __builtin_amdgcn_mfma_f32_32x32x16_bf16(ah[ti], bl_, acc[ti], 0, 0, 0);
            acc[ti] = __builtin_amdgcn_mfma_f32_32x32x16_bf16(al[ti], bh_, acc[ti], 0, 0, 0);
        }
    }

    // ---- epilogue: D[row = o (reg pattern), col = s = s0+ln] ----
    const int sg = s0 + ln;
#pragma unroll
    for (int ti = 0; ti < 2; ++ti)
#pragma unroll
        for (int reg = 0; reg < 16; ++reg) {
            const int o = w * 64 + ti * 32 + (reg & 3) + 8 * (reg >> 2) + 4 * h;
            const size_t SLB = (size_t)((b * 4 + (o >> 6)) * 64 + (o & 63)) * 4096;
            const float av0 = acc[ti][reg] + bias[o];
            if (proj == 2) {
                const size_t ui = SLB + (size_t)((sg >> 9) * 64 + (sg & 63)) * 8 + ((sg >> 6) & 7);
                Vpk[ui] = f16b(av0);
            } else {
                const float av = (proj == 0) ? av0 * L2E : av0;
                const size_t ui = SLB + (size_t)(((sg >> 3) & 7) * 64 + (sg >> 6)) * 8 + (sg & 7);
                u16* dst = (proj == 0) ? Kpk : Qpk;
                dst[ui] = f16b(av);
            }
        }
}

// ---------------------------------------------------------------------------
// flash3 (R12): K single f16 -> QK^T is 8 MFMA/jt (was 16). Grid (bh, tq-half,
// t) = 1024 blocks; the 4 waves of a block each take 8 tq and the block
// turn-taking-reduces the 4 O-tiles in LDS (16 KB) -> ONE coalesced f32 tile
// per half (no more 8x f16 scatter partials). zpart keeps the 8-qq layout.
// S^T = Q*K^T (32x32x16 f16, C-init = -48*log2e), P = exp2 (builtin, single
// v_exp), in-register P->A-frag via cvt_pkrtz + shfl_xor(32) + half-select,
// O += P*V, setprio(1) around MFMA clusters (T5 — no barriers in main loop).
// NOTE: launch_bounds stays (256,2) — (256,4) caused the R8 spill disaster.
// ---------------------------------------------------------------------------
__global__ __launch_bounds__(256, 2) void flash3(
    const u16* __restrict__ Kpk, const u16* __restrict__ Qpk,
    const u16* __restrict__ Vpk,
    float* __restrict__ Opf, float* __restrict__ zpart)
{
    __shared__ float Osum[64 * 64];   // 16 KB cross-wave O reduce

    const int tid = threadIdx.x;
    const int w = tid >> 6, l = tid & 63;
    const int h = l >> 5, ln = l & 31;
    const int id = blockIdx.x;
    const int bh = id & 7, half = (id >> 3) & 1, t = id >> 4;   // t 0..63
    const int b = bh >> 2, hd = bh & 3;
    const int qq = half * 4 + w;       // tq eighth owned by this wave

    const u16* Kh = Kpk + (size_t)(bh * 64 + t) * 4096;

    half8 kf[2][4];
#pragma unroll
    for (int rt = 0; rt < 2; ++rt)
#pragma unroll
        for (int ks = 0; ks < 4; ++ks)
            kf[rt][ks] = ld_frag(Kh + ((ks * 2 + h) * 64 + rt * 32 + ln) * 8);

    f32x16 oacc[2][2];
#pragma unroll
    for (int rt = 0; rt < 2; ++rt)
#pragma unroll
        for (int ft = 0; ft < 2; ++ft)
#pragma unroll
            for (int i = 0; i < 16; ++i) oacc[rt][ft][i] = 0.f;
    float zacc[2] = {0.f, 0.f};

    for (int it = 0; it < 8; ++it) {
        const int tq = qq * 8 + it;
        const u16* Qt = Qpk + (size_t)(bh * 64 + tq) * 4096;
        const u16* Vt = Vpk + (size_t)(bh * 64 + tq) * 4096;
#pragma unroll
        for (int jt = 0; jt < 2; ++jt) {
            half8 qf[4];
#pragma unroll
            for (int ks = 0; ks < 4; ++ks)
                qf[ks] = ld_frag(Qt + ((ks * 2 + h) * 64 + jt * 32 + ln) * 8);

            f32x16 sa[2];
#pragma unroll
            for (int rt = 0; rt < 2; ++rt)
#pragma unroll
                for (int i = 0; i < 16; ++i) sa[rt][i] = -SH2;
            __builtin_amdgcn_s_setprio(1);
#pragma unroll
            for (int ks = 0; ks < 4; ++ks) {
                sa[0] = __builtin_amdgcn_mfma_f32_32x32x16_f16(qf[ks], kf[0][ks], sa[0], 0, 0, 0);
                sa[1] = __builtin_amdgcn_mfma_f32_32x32x16_f16(qf[ks], kf[1][ks], sa[1], 0, 0, 0);
            }
            __builtin_amdgcn_s_setprio(0);

            half8 vf[2][2];
#pragma unroll
            for (int js = 0; js < 2; ++js)
#pragma unroll
                for (int ft = 0; ft < 2; ++ft)
                    vf[js][ft] = ld_frag(Vt + (((jt * 2 + js) * 2 + h) * 64 + ft * 32 + ln) * 8);

#pragma unroll
            for (int rt = 0; rt < 2; ++rt) {
                float p[16]; float zs = 0.f;
#pragma unroll
                for (int i = 0; i < 16; ++i) {
                    p[i] = __builtin_amdgcn_exp2f(sa[rt][i]);
                    zs += p[i];
                }
                zacc[rt] += zs;
                u32 wd[8], sw[8];
#pragma unroll
                for (int i = 0; i < 8; ++i) wd[i] = pkrtz(p[2 * i], p[2 * i + 1]);
#pragma unroll
                for (int i = 0; i < 8; ++i) sw[i] = (u32)__shfl_xor((int)wd[i], 32);
                int4 c0 = make_int4((int)(h ? sw[2] : wd[0]), (int)(h ? sw[3] : wd[1]),
                                    (int)(h ? wd[2] : sw[0]), (int)(h ? wd[3] : sw[1]));
                int4 c1 = make_int4((int)(h ? sw[6] : wd[4]), (int)(h ? sw[7] : wd[5]),
                                    (int)(h ? wd[6] : sw[4]), (int)(h ? wd[7] : sw[5]));
                const half8 pf0 = __builtin_bit_cast(half8, c0);
                const half8 pf1 = __builtin_bit_cast(half8, c1);
                __builtin_amdgcn_s_setprio(1);
                oacc[rt][0] = __builtin_amdgcn_mfma_f32_32x32x16_f16(pf0, vf[0][0], oacc[rt][0], 0, 0, 0);
                oacc[rt][0] = __builtin_amdgcn_mfma_f32_32x32x16_f16(pf1, vf[1][0], oacc[rt][0], 0, 0, 0);
                oacc[rt][1] = __builtin_amdgcn_mfma_f32_32x32x16_f16(pf0, vf[0][1], oacc[rt][1], 0, 0, 0);
                oacc[rt][1] = __builtin_amdgcn_mfma_f32_32x32x16_f16(pf1, vf[1][1], oacc[rt][1], 0, 0, 0);
                __builtin_amdgcn_s_setprio(0);
            }
        }
    }

    // ---- per-row Z partials (8-qq layout kept for reduce_kernel) ----
#pragma unroll
    for (int rt = 0; rt < 2; ++rt) {
        const float z2 = zacc[rt] + __shfl_xor(zacc[rt], 32);
        if (h == 0)
            zpart[((size_t)qq * 8 + bh) * NSP + t * 64 + rt * 32 + ln] = z2;
    }

    // ---- cross-wave O reduce in LDS (turn-taking), then ONE f32 write ----
    for (int turn = 0; turn < 4; ++turn) {
        if (w == turn) {
#pragma unroll
            for (int rt = 0; rt < 2; ++rt)
#pragma unroll
                for (int ft = 0; ft < 2; ++ft)
#pragma unroll
                    for (int reg = 0; reg < 16; ++reg) {
                        const int row = rt * 32 + (reg & 3) + 8 * (reg >> 2) + 4 * h;
                        const int col = ft * 32 + ln;
                        if (turn == 0) Osum[row * 64 + col] = oacc[rt][ft][reg];
                        else           Osum[row * 64 + col] += oacc[rt][ft][reg];
                    }
        }
        __syncthreads();
    }
    float* Od = Opf + (size_t)half * ((size_t)2 * CC * NSP)
              + ((size_t)(b * CC + hd * 64 + t)) * NSP;
#pragma unroll
    for (int i = 0; i < 4; ++i) {
        const int idx = tid + 256 * i;                 // 1024 f32x4 chunks
        *(f32x4*)(Od + idx * 4) = *(const f32x4*)(Osum + idx * 4);
    }
}

// ---------------------------------------------------------------------------
__global__ __launch_bounds__(256) void reduce_kernel(
    const float* __restrict__ zp, float* __restrict__ coef)
{
    __shared__ float red[256];
    const int tid = threadIdx.x, bh = blockIdx.x;
    float lz = 0.f;
    for (int i = tid; i < 8 * NSP; i += 256) {
        const int qq = i >> 12, r = i & 4095;
        lz += zp[((size_t)qq * 8 + bh) * NSP + r];
    }
    red[tid] = lz; __syncthreads();
    for (int s = 128; s > 0; s >>= 1) {
        if (tid < s) red[tid] += red[tid + s];
        __syncthreads();
    }
    if (tid == 0) coef[bh] = 1.f / red[0];
}

// ---------------------------------------------------------------------------
// conv_out: out = W4 . ((Opf0 + Opf1) * coef) + b4, f32, MFMA.
// Stage: 2 coalesced f32 loads/elem (was 8 scalar u16 partial loads).
// Block 256 thr / 4 waves; tile = 128 o (oh half) x 32 s; grid (128,2,2)=512.
// ---------------------------------------------------------------------------
__global__ __launch_bounds__(256) void conv_out(
    const float* __restrict__ Opf,
    const u16* __restrict__ Wpk_hi, const u16* __restrict__ Wpk_lo,
    const float* __restrict__ b4, const float* __restrict__ coef,
    float* __restrict__ out)
{
    __shared__ __align__(16) u16 Xhi[32 * 256];   // 16 KB
    __shared__ __align__(16) u16 Xlo[32 * 256];   // 16 KB

    const int tid = threadIdx.x;
    const int w = tid >> 6, l = tid & 63;
    const int h = l >> 5, ln = l & 31;
    const int st = blockIdx.x;           // 0..127
    const int oh = blockIdx.y;           // o half
    const int b = blockIdx.z;
    const int s0 = st * 32;

    const u16* Wh = Wpk_hi + 3 * 65536;
    const u16* Wl = Wpk_lo + 3 * 65536;
    const size_t TENf = (size_t)2 * CC * NSP;

    // ---- stage: (Opf0 + Opf1) * coef -> bf16 hi/lo LDS ----
    const float cf = coef[b * 4 + w];
#pragma unroll
    for (int i = 0; i < 4; ++i) {
        const int c0 = w * 64 + (h * 4 + i) * 8;
        float xv[8];
#pragma unroll
        for (int cc = 0; cc < 8; ++cc) {
            const size_t base = ((size_t)b * CC + c0 + cc) * NSP + s0 + ln;
            xv[cc] = (Opf[base] + Opf[TENf + base]) * cf;
        }
        u32 hw[4], lw[4];
#pragma unroll
        for (int p2 = 0; p2 < 4; ++p2) {
            const u16 h0 = bf16rne(xv[2 * p2]);
            const u16 h1 = bf16rne(xv[2 * p2 + 1]);
            const u16 l0 = bf16rne(xv[2 * p2]     - __uint_as_float((u32)h0 << 16));
            const u16 l1 = bf16rne(xv[2 * p2 + 1] - __uint_as_float((u32)h1 << 16));
            hw[p2] = (u32)h0 | ((u32)h1 << 16);
            lw[p2] = (u32)l0 | ((u32)l1 << 16);
        }
        const int off = ((ln * 256 + c0) * 2) ^ ((ln & 7) << 4);
        *(uint4*)((char*)Xhi + off) = make_uint4(hw[0], hw[1], hw[2], hw[3]);
        *(uint4*)((char*)Xlo + off) = make_uint4(lw[0], lw[1], lw[2], lw[3]);
    }
    __syncthreads();

    f32x16 acc;
#pragma unroll
    for (int i = 0; i < 16; ++i) acc[i] = 0.f;

#pragma unroll 2
    for (int kk = 0; kk < 16; ++kk) {
        const int kc = kk * 16 + h * 8;
        const size_t fi = ((size_t)(kc >> 3) * 256 + oh * 128 + w * 32 + ln) * 8;
        const short8 ah = ld_bfrag(Wh + fi);
        const short8 al = ld_bfrag(Wl + fi);
        const int off = ((ln * 256 + kc) * 2) ^ ((ln & 7) << 4);
        const short8 bh_ = *(const short8*)((const char*)Xhi + off);
        const short8 bl_ = *(const short8*)((const char*)Xlo + off);
        acc = __builtin_amdgcn_mfma_f32_32x32x16_bf16(ah, bh_, acc, 0, 0, 0);
        acc = __builtin_amdgcn_mfma_f32_32x32x16_bf16(ah, bl_, acc, 0, 0, 0);
        acc = __builtin_amdgcn_mfma_f32_32x32x16_bf16(al, bh_, acc, 0, 0, 0);
    }

    const int sg = s0 + ln;
#pragma unroll
    for (int reg = 0; reg < 16; ++reg) {
        const int o = oh * 128 + w * 32 + (reg & 3) + 8 * (reg >> 2) + 4 * h;
        out[((size_t)b * CC + o) * NSP + sg] = acc[reg] + b4[o];
    }
}

// ---------------------------------------------------------------------------
extern "C" void kernel_launch(void* const* d_in, const int* in_sizes, int n_in,
                              void* d_out, int out_size, void* d_ws, size_t ws_size,
                              hipStream_t stream)
{
    (void)in_sizes; (void)n_in; (void)out_size; (void)ws_size;
    const float* in1 = (const float*)d_in[0];
    const float* in2 = (const float*)d_in[1];
    const float* W1 = (const float*)d_in[2]; const float* b1 = (const float*)d_in[3];
    const float* W2 = (const float*)d_in[4]; const float* b2 = (const float*)d_in[5];
    const float* W3 = (const float*)d_in[6]; const float* b3 = (const float*)d_in[7];
    const float* W4 = (const float*)d_in[8]; const float* b4 = (const float*)d_in[9];
    float* out = (float*)d_out;

    const size_t TEN = (size_t)2 * CC * NSP;          // 2,097,152 elements
    char* p = (char*)d_ws;
    u16* Kpk = (u16*)p; p += TEN * 2;                 // 4 MB
    u16* Qpk = (u16*)p; p += TEN * 2;                 // 4 MB
    u16* Vpk = (u16*)p; p += TEN * 2;                 // 4 MB
    u16* Wph = (u16*)p; p += 4 * 65536 * 2;           // 512 KB
    u16* Wpl = (u16*)p; p += 4 * 65536 * 2;           // 512 KB
    float* Opf = (float*)p; p += 2 * TEN * 4;         // 16 MB (2 f32 halves)
    float* zpart = (float*)p; p += (size_t)8 * 8 * NSP * 4;   // 1 MB
    float* coef  = (float*)p;

    wpack<<<dim3(64, 4), 256, 0, stream>>>(W1, W2, W3, W4, Wph, Wpl);
    conv_qkv<<<dim3(128, 3, 2), 256, 0, stream>>>(
        in1, in2, Wph, Wpl, b1, b2, b3, Kpk, Qpk, Vpk);
    flash3<<<dim3(1024), 256, 0, stream>>>(Kpk, Qpk, Vpk, Opf, zpart);
    reduce_kernel<<<dim3(8), 256, 0, stream>>>(zpart, coef);
    conv_out<<<dim3(128, 2, 2), 256, 0, stream>>>(Opf, Wph, Wpl, b4, coef, out);
}